// Round 2
// baseline (3288.314 us; speedup 1.0000x reference)
//
#include <hip/hip_runtime.h>
#include <hip/hip_bf16.h>
#include <math.h>

// Problem constants
#define BATCH   2
#define NTOK    2048
#define DMODEL  1024
#define HEADS   16
#define DHEAD   64
#define KSEL    32
#define MROWS   (BATCH * NTOK)   // 4096

// ---------------------------------------------------------------------------
// GEMM: C[m,o] = sum_k A[m,k] * W[o,k] + bias[o]
// ---------------------------------------------------------------------------
__global__ __launch_bounds__(256) void gemm_nt(const float* __restrict__ A,
                                               const float* __restrict__ W,
                                               const float* __restrict__ bias,
                                               float* __restrict__ out,
                                               int scatter)
{
    __shared__ float As[16][65];  // As[k][m]
    __shared__ float Bs[16][65];  // Bs[k][o]

    const int tid = threadIdx.x;
    const int bm = blockIdx.x * 64;
    const int bo = blockIdx.y * 64;
    const int tx = tid & 15;
    const int ty = tid >> 4;

    const int lr = tid >> 2;
    const int lc = (tid & 3) << 2;

    float acc[4][4];
#pragma unroll
    for (int i = 0; i < 4; ++i)
#pragma unroll
        for (int j = 0; j < 4; ++j) acc[i][j] = 0.f;

    for (int k0 = 0; k0 < DMODEL; k0 += 16) {
        float4 av = *(const float4*)(A + (size_t)(bm + lr) * DMODEL + k0 + lc);
        float4 bv = *(const float4*)(W + (size_t)(bo + lr) * DMODEL + k0 + lc);
        As[lc + 0][lr] = av.x; As[lc + 1][lr] = av.y;
        As[lc + 2][lr] = av.z; As[lc + 3][lr] = av.w;
        Bs[lc + 0][lr] = bv.x; Bs[lc + 1][lr] = bv.y;
        Bs[lc + 2][lr] = bv.z; Bs[lc + 3][lr] = bv.w;
        __syncthreads();
#pragma unroll
        for (int kk = 0; kk < 16; ++kk) {
            float a0 = As[kk][ty * 4 + 0];
            float a1 = As[kk][ty * 4 + 1];
            float a2 = As[kk][ty * 4 + 2];
            float a3 = As[kk][ty * 4 + 3];
            float b0 = Bs[kk][tx * 4 + 0];
            float b1 = Bs[kk][tx * 4 + 1];
            float b2 = Bs[kk][tx * 4 + 2];
            float b3 = Bs[kk][tx * 4 + 3];
            acc[0][0] += a0 * b0; acc[0][1] += a0 * b1; acc[0][2] += a0 * b2; acc[0][3] += a0 * b3;
            acc[1][0] += a1 * b0; acc[1][1] += a1 * b1; acc[1][2] += a1 * b2; acc[1][3] += a1 * b3;
            acc[2][0] += a2 * b0; acc[2][1] += a2 * b1; acc[2][2] += a2 * b2; acc[2][3] += a2 * b3;
            acc[3][0] += a3 * b0; acc[3][1] += a3 * b1; acc[3][2] += a3 * b2; acc[3][3] += a3 * b3;
        }
        __syncthreads();
    }

#pragma unroll
    for (int i = 0; i < 4; ++i) {
        const int m = bm + ty * 4 + i;
#pragma unroll
        for (int j = 0; j < 4; ++j) {
            const int o = bo + tx * 4 + j;
            const float v = acc[i][j] + bias[o];
            if (scatter) {
                const int bb = m >> 11;
                const int n  = m & 2047;
                const int h  = o >> 6;
                const int d  = o & 63;
                out[(((size_t)(bb * HEADS + h)) * NTOK + n) * DHEAD + d] = v;
            } else {
                out[(size_t)m * DMODEL + o] = v;
            }
        }
    }
}

// ---------------------------------------------------------------------------
// score_kernel: S[bh, q, k] = (Q[bh,q,:] . K[bh,k,:]) * 0.125
// 64x64 tile per block, K-dim = 64 (DHEAD). Upper-triangle tiles skipped;
// within the diagonal tile the k>q entries are garbage but never read.
// grid = (32 kt, 32 qt, 32 bh)
// ---------------------------------------------------------------------------
__global__ __launch_bounds__(256) void score_kernel(const float* __restrict__ Q,
                                                    const float* __restrict__ K,
                                                    float* __restrict__ S)
{
    const int kt = blockIdx.x;
    const int qt = blockIdx.y;
    if (kt > qt) return;
    const int bh = blockIdx.z;

    __shared__ float As[16][65];  // As[k][q]
    __shared__ float Bs[16][65];  // Bs[k][key]

    const int tid = threadIdx.x;
    const int tx = tid & 15;
    const int ty = tid >> 4;
    const int lr = tid >> 2;
    const int lc = (tid & 3) << 2;

    const float* Qb = Q + ((size_t)bh * NTOK + qt * 64) * DHEAD;
    const float* Kb = K + ((size_t)bh * NTOK + kt * 64) * DHEAD;

    float acc[4][4];
#pragma unroll
    for (int i = 0; i < 4; ++i)
#pragma unroll
        for (int j = 0; j < 4; ++j) acc[i][j] = 0.f;

#pragma unroll
    for (int k0 = 0; k0 < DHEAD; k0 += 16) {
        float4 av = *(const float4*)(Qb + (size_t)lr * DHEAD + k0 + lc);
        float4 bv = *(const float4*)(Kb + (size_t)lr * DHEAD + k0 + lc);
        As[lc + 0][lr] = av.x; As[lc + 1][lr] = av.y;
        As[lc + 2][lr] = av.z; As[lc + 3][lr] = av.w;
        Bs[lc + 0][lr] = bv.x; Bs[lc + 1][lr] = bv.y;
        Bs[lc + 2][lr] = bv.z; Bs[lc + 3][lr] = bv.w;
        __syncthreads();
#pragma unroll
        for (int kk = 0; kk < 16; ++kk) {
            float a0 = As[kk][ty * 4 + 0];
            float a1 = As[kk][ty * 4 + 1];
            float a2 = As[kk][ty * 4 + 2];
            float a3 = As[kk][ty * 4 + 3];
            float b0 = Bs[kk][tx * 4 + 0];
            float b1 = Bs[kk][tx * 4 + 1];
            float b2 = Bs[kk][tx * 4 + 2];
            float b3 = Bs[kk][tx * 4 + 3];
            acc[0][0] += a0 * b0; acc[0][1] += a0 * b1; acc[0][2] += a0 * b2; acc[0][3] += a0 * b3;
            acc[1][0] += a1 * b0; acc[1][1] += a1 * b1; acc[1][2] += a1 * b2; acc[1][3] += a1 * b3;
            acc[2][0] += a2 * b0; acc[2][1] += a2 * b1; acc[2][2] += a2 * b2; acc[2][3] += a2 * b3;
            acc[3][0] += a3 * b0; acc[3][1] += a3 * b1; acc[3][2] += a3 * b2; acc[3][3] += a3 * b3;
        }
        __syncthreads();
    }

    float* Srow = S + (size_t)bh * NTOK * NTOK;
#pragma unroll
    for (int i = 0; i < 4; ++i) {
        const int q = qt * 64 + ty * 4 + i;
#pragma unroll
        for (int j = 0; j < 4; ++j) {
            const int k = kt * 64 + tx * 4 + j;
            Srow[(size_t)q * NTOK + k] = acc[i][j] * 0.125f;
        }
    }
}

// ---------------------------------------------------------------------------
// select_kernel: per (b,q): read precomputed S rows (coalesced), top-32
// extraction, softmax, AV, attn-mean. One block per (b,q), wave w handles
// heads w, 4+w, 8+w, 12+w.
// ---------------------------------------------------------------------------
__global__ __launch_bounds__(256) void select_kernel(const float* __restrict__ S,
                                                     const float* __restrict__ V,
                                                     float* __restrict__ ctx,
                                                     float* __restrict__ attn_out)
{
    const int blk = blockIdx.x;
    const int b = blk >> 11;
    const int q = blk & (NTOK - 1);
    const int tid = threadIdx.x;
    const int wave = tid >> 6;
    const int lane = tid & 63;

    __shared__ float sc[4][NTOK];
    __shared__ float am[NTOK];
    __shared__ float selv[4][KSEL];
    __shared__ int   seli[4][KSEL];
    __shared__ float selw[4][KSEL];

    for (int j = tid; j < NTOK; j += 256) am[j] = 0.f;
    __syncthreads();

    const int L = q + 1;
    const int nsel = (L < KSEL) ? L : KSEL;

    for (int hg = 0; hg < 4; ++hg) {
        const int h = hg * 4 + wave;
        const size_t bh = (size_t)(b * HEADS + h);
        const float* Srow = S + (bh * NTOK + q) * NTOK;
        const float* Vb = V + bh * NTOK * DHEAD;

        // coalesced read of the precomputed score row
        float lm = -INFINITY; int li = -1;
        for (int j = lane; j < L; j += 64) {
            const float s = Srow[j];
            sc[wave][j] = s;
            if (s > lm) { lm = s; li = j; }
        }

        // iterative top-nsel extraction (wave-synchronous)
        for (int it = 0; it < nsel; ++it) {
            float bmv = lm; int bi = li;
#pragma unroll
            for (int mask = 1; mask < 64; mask <<= 1) {
                const float ov = __shfl_xor(bmv, mask, 64);
                const int   oi = __shfl_xor(bi, mask, 64);
                if (ov > bmv || (ov == bmv && (unsigned)oi < (unsigned)bi)) {
                    bmv = ov; bi = oi;
                }
            }
            if (lane == (bi & 63)) {
                sc[wave][bi] = -INFINITY;
                lm = -INFINITY; li = -1;
                for (int j = lane; j < L; j += 64) {
                    const float s = sc[wave][j];
                    if (s > lm) { lm = s; li = j; }
                }
            }
            if (lane == 0) { selv[wave][it] = bmv; seli[wave][it] = bi; }
        }

        // softmax over selected
        const float m = selv[wave][0];
        float e = 0.f;
        if (lane < nsel) e = expf(selv[wave][lane] - m);
        float Z = e;
#pragma unroll
        for (int mask = 1; mask < 32; mask <<= 1) Z += __shfl_xor(Z, mask, 64);
        if (lane < nsel) {
            const float w = e / Z;
            selw[wave][lane] = w;
            atomicAdd(&am[seli[wave][lane]], w);
        }

        // ctx[b,q,h,:] = sum_i w_i * V[idx_i,:]   (lane = d)
        float acc = 0.f;
        for (int i = 0; i < nsel; ++i) {
            const int idx = seli[wave][i];
            const float w = selw[wave][i];
            acc += w * Vb[(size_t)idx * DHEAD + lane];
        }
        ctx[(((size_t)(b * NTOK + q)) * HEADS + h) * DHEAD + lane] = acc;
    }

    __syncthreads();
    const float invH = 1.0f / (float)HEADS;
    float* arow = attn_out + ((size_t)(b * NTOK + q)) * NTOK;
    for (int j = tid; j < NTOK; j += 256) arow[j] = am[j] * invH;
}

// ---------------------------------------------------------------------------
// Fallback fused attention (round-1 kernel) — used when ws is too small to
// materialize the score matrix.
// ---------------------------------------------------------------------------
__global__ __launch_bounds__(256) void attn_kernel(const float* __restrict__ Q,
                                                   const float* __restrict__ K,
                                                   const float* __restrict__ V,
                                                   float* __restrict__ ctx,
                                                   float* __restrict__ attn_out)
{
    const int blk = blockIdx.x;
    const int b = blk >> 11;
    const int q = blk & (NTOK - 1);
    const int tid = threadIdx.x;
    const int wave = tid >> 6;
    const int lane = tid & 63;

    __shared__ float sc[4][NTOK];
    __shared__ float am[NTOK];
    __shared__ float selv[4][KSEL];
    __shared__ int   seli[4][KSEL];
    __shared__ float selw[4][KSEL];

    for (int j = tid; j < NTOK; j += 256) am[j] = 0.f;
    __syncthreads();

    const int L = q + 1;
    const int nsel = (L < KSEL) ? L : KSEL;

    for (int hg = 0; hg < 4; ++hg) {
        const int h = hg * 4 + wave;
        const size_t bh = (size_t)(b * HEADS + h);
        const float* Qrow = Q + (bh * NTOK + q) * DHEAD;
        const float* Kb = K + bh * NTOK * DHEAD;
        const float* Vb = V + bh * NTOK * DHEAD;

        float4 qr[16];
#pragma unroll
        for (int d4 = 0; d4 < 16; ++d4) qr[d4] = ((const float4*)Qrow)[d4];

        float lm = -INFINITY; int li = -1;
        for (int j = lane; j < L; j += 64) {
            const float4* kr = (const float4*)(Kb + (size_t)j * DHEAD);
            float a0 = 0.f, a1 = 0.f, a2 = 0.f, a3 = 0.f;
#pragma unroll
            for (int d4 = 0; d4 < 16; ++d4) {
                const float4 kk = kr[d4];
                a0 += qr[d4].x * kk.x;
                a1 += qr[d4].y * kk.y;
                a2 += qr[d4].z * kk.z;
                a3 += qr[d4].w * kk.w;
            }
            const float s = (a0 + a1 + a2 + a3) * 0.125f;
            sc[wave][j] = s;
            if (s > lm) { lm = s; li = j; }
        }

        for (int it = 0; it < nsel; ++it) {
            float bmv = lm; int bi = li;
#pragma unroll
            for (int mask = 1; mask < 64; mask <<= 1) {
                const float ov = __shfl_xor(bmv, mask, 64);
                const int   oi = __shfl_xor(bi, mask, 64);
                if (ov > bmv || (ov == bmv && (unsigned)oi < (unsigned)bi)) {
                    bmv = ov; bi = oi;
                }
            }
            if (lane == (bi & 63)) {
                sc[wave][bi] = -INFINITY;
                lm = -INFINITY; li = -1;
                for (int j = lane; j < L; j += 64) {
                    const float s = sc[wave][j];
                    if (s > lm) { lm = s; li = j; }
                }
            }
            if (lane == 0) { selv[wave][it] = bmv; seli[wave][it] = bi; }
        }

        const float m = selv[wave][0];
        float e = 0.f;
        if (lane < nsel) e = expf(selv[wave][lane] - m);
        float Z = e;
#pragma unroll
        for (int mask = 1; mask < 32; mask <<= 1) Z += __shfl_xor(Z, mask, 64);
        if (lane < nsel) {
            const float w = e / Z;
            selw[wave][lane] = w;
            atomicAdd(&am[seli[wave][lane]], w);
        }

        float acc = 0.f;
        for (int i = 0; i < nsel; ++i) {
            const int idx = seli[wave][i];
            const float w = selw[wave][i];
            acc += w * Vb[(size_t)idx * DHEAD + lane];
        }
        ctx[(((size_t)(b * NTOK + q)) * HEADS + h) * DHEAD + lane] = acc;
    }

    __syncthreads();
    const float invH = 1.0f / (float)HEADS;
    float* arow = attn_out + ((size_t)(b * NTOK + q)) * NTOK;
    for (int j = tid; j < NTOK; j += 256) arow[j] = am[j] * invH;
}

// ---------------------------------------------------------------------------
extern "C" void kernel_launch(void* const* d_in, const int* in_sizes, int n_in,
                              void* d_out, int out_size, void* d_ws, size_t ws_size,
                              hipStream_t stream) {
    const float* x  = (const float*)d_in[0];
    const float* Wq = (const float*)d_in[1];
    const float* bq = (const float*)d_in[2];
    const float* Wk = (const float*)d_in[3];
    const float* bk = (const float*)d_in[4];
    const float* Wv = (const float*)d_in[5];
    const float* bv = (const float*)d_in[6];
    const float* Wo = (const float*)d_in[7];
    const float* bo = (const float*)d_in[8];

    const size_t SZ = (size_t)MROWS * DMODEL;  // 4,194,304 floats
    float* ws  = (float*)d_ws;
    float* Qws = ws;
    float* Kws = ws + SZ;
    float* Vws = ws + 2 * SZ;
    float* ctx = ws + 3 * SZ;
    float* Sws = ws + 4 * SZ;   // score matrix [32 bh][2048][2048] fp32

    const size_t need_bytes = (4 * SZ + (size_t)BATCH * HEADS * NTOK * NTOK) * sizeof(float);

    float* y    = (float*)d_out;
    float* attn = y + (size_t)BATCH * NTOK * DMODEL;

    dim3 gemm_grid(MROWS / 64, DMODEL / 64);
    gemm_nt<<<gemm_grid, 256, 0, stream>>>(x, Wq, bq, Qws, 1);
    gemm_nt<<<gemm_grid, 256, 0, stream>>>(x, Wk, bk, Kws, 1);
    gemm_nt<<<gemm_grid, 256, 0, stream>>>(x, Wv, bv, Vws, 1);

    if (ws_size >= need_bytes) {
        dim3 sgrid(NTOK / 64, NTOK / 64, BATCH * HEADS);
        score_kernel<<<sgrid, 256, 0, stream>>>(Qws, Kws, Sws);
        select_kernel<<<BATCH * NTOK, 256, 0, stream>>>(Sws, Vws, ctx, attn);
    } else {
        attn_kernel<<<BATCH * NTOK, 256, 0, stream>>>(Qws, Kws, Vws, ctx, attn);
    }

    gemm_nt<<<gemm_grid, 256, 0, stream>>>(ctx, Wo, bo, y, 0);
}

// Round 3
// 2921.992 us; speedup vs baseline: 1.1254x; 1.1254x over previous
//
#include <hip/hip_runtime.h>
#include <hip/hip_bf16.h>
#include <math.h>

// Problem constants
#define BATCH   2
#define NTOK    2048
#define DMODEL  1024
#define HEADS   16
#define DHEAD   64
#define KSEL    32
#define MROWS   (BATCH * NTOK)   // 4096

// ---------------------------------------------------------------------------
// GEMM: C[m,o] = sum_k A[m,k] * W[o,k] + bias[o]
// ---------------------------------------------------------------------------
__global__ __launch_bounds__(256) void gemm_nt(const float* __restrict__ A,
                                               const float* __restrict__ W,
                                               const float* __restrict__ bias,
                                               float* __restrict__ out,
                                               int scatter)
{
    __shared__ float As[16][65];  // As[k][m]
    __shared__ float Bs[16][65];  // Bs[k][o]

    const int tid = threadIdx.x;
    const int bm = blockIdx.x * 64;
    const int bo = blockIdx.y * 64;
    const int tx = tid & 15;
    const int ty = tid >> 4;

    const int lr = tid >> 2;
    const int lc = (tid & 3) << 2;

    float acc[4][4];
#pragma unroll
    for (int i = 0; i < 4; ++i)
#pragma unroll
        for (int j = 0; j < 4; ++j) acc[i][j] = 0.f;

    for (int k0 = 0; k0 < DMODEL; k0 += 16) {
        float4 av = *(const float4*)(A + (size_t)(bm + lr) * DMODEL + k0 + lc);
        float4 bv = *(const float4*)(W + (size_t)(bo + lr) * DMODEL + k0 + lc);
        As[lc + 0][lr] = av.x; As[lc + 1][lr] = av.y;
        As[lc + 2][lr] = av.z; As[lc + 3][lr] = av.w;
        Bs[lc + 0][lr] = bv.x; Bs[lc + 1][lr] = bv.y;
        Bs[lc + 2][lr] = bv.z; Bs[lc + 3][lr] = bv.w;
        __syncthreads();
#pragma unroll
        for (int kk = 0; kk < 16; ++kk) {
            float a0 = As[kk][ty * 4 + 0];
            float a1 = As[kk][ty * 4 + 1];
            float a2 = As[kk][ty * 4 + 2];
            float a3 = As[kk][ty * 4 + 3];
            float b0 = Bs[kk][tx * 4 + 0];
            float b1 = Bs[kk][tx * 4 + 1];
            float b2 = Bs[kk][tx * 4 + 2];
            float b3 = Bs[kk][tx * 4 + 3];
            acc[0][0] += a0 * b0; acc[0][1] += a0 * b1; acc[0][2] += a0 * b2; acc[0][3] += a0 * b3;
            acc[1][0] += a1 * b0; acc[1][1] += a1 * b1; acc[1][2] += a1 * b2; acc[1][3] += a1 * b3;
            acc[2][0] += a2 * b0; acc[2][1] += a2 * b1; acc[2][2] += a2 * b2; acc[2][3] += a2 * b3;
            acc[3][0] += a3 * b0; acc[3][1] += a3 * b1; acc[3][2] += a3 * b2; acc[3][3] += a3 * b3;
        }
        __syncthreads();
    }

#pragma unroll
    for (int i = 0; i < 4; ++i) {
        const int m = bm + ty * 4 + i;
#pragma unroll
        for (int j = 0; j < 4; ++j) {
            const int o = bo + tx * 4 + j;
            const float v = acc[i][j] + bias[o];
            if (scatter) {
                const int bb = m >> 11;
                const int n  = m & 2047;
                const int h  = o >> 6;
                const int d  = o & 63;
                out[(((size_t)(bb * HEADS + h)) * NTOK + n) * DHEAD + d] = v;
            } else {
                out[(size_t)m * DMODEL + o] = v;
            }
        }
    }
}

// ---------------------------------------------------------------------------
// score_chunk: S[bh, q_local, k] = (Q[bh, q0+q_local, :] . K[bh, k, :]) / 8
// for q_local in [0, QC). 64x64 tiles; upper-triangle (non-causal) tiles
// skipped. grid = ((q0+QC)/64 kt, QC/64 qt, 32 bh).
// ---------------------------------------------------------------------------
__global__ __launch_bounds__(256) void score_chunk(const float* __restrict__ Q,
                                                   const float* __restrict__ K,
                                                   float* __restrict__ S,
                                                   int q0, int QC)
{
    const int kt = blockIdx.x;
    const int qt = blockIdx.y;                 // local q tile
    const int qt_g = (q0 >> 6) + qt;           // global q tile
    if (kt > qt_g) return;
    const int bh = blockIdx.z;

    __shared__ float As[16][65];  // As[d][q]
    __shared__ float Bs[16][65];  // Bs[d][k]

    const int tid = threadIdx.x;
    const int tx = tid & 15;
    const int ty = tid >> 4;
    const int lr = tid >> 2;
    const int lc = (tid & 3) << 2;

    const float* Qb = Q + ((size_t)bh * NTOK + q0 + qt * 64) * DHEAD;
    const float* Kb = K + ((size_t)bh * NTOK + kt * 64) * DHEAD;

    float acc[4][4];
#pragma unroll
    for (int i = 0; i < 4; ++i)
#pragma unroll
        for (int j = 0; j < 4; ++j) acc[i][j] = 0.f;

#pragma unroll
    for (int k0 = 0; k0 < DHEAD; k0 += 16) {
        float4 av = *(const float4*)(Qb + (size_t)lr * DHEAD + k0 + lc);
        float4 bv = *(const float4*)(Kb + (size_t)lr * DHEAD + k0 + lc);
        As[lc + 0][lr] = av.x; As[lc + 1][lr] = av.y;
        As[lc + 2][lr] = av.z; As[lc + 3][lr] = av.w;
        Bs[lc + 0][lr] = bv.x; Bs[lc + 1][lr] = bv.y;
        Bs[lc + 2][lr] = bv.z; Bs[lc + 3][lr] = bv.w;
        __syncthreads();
#pragma unroll
        for (int kk = 0; kk < 16; ++kk) {
            float a0 = As[kk][ty * 4 + 0];
            float a1 = As[kk][ty * 4 + 1];
            float a2 = As[kk][ty * 4 + 2];
            float a3 = As[kk][ty * 4 + 3];
            float b0 = Bs[kk][tx * 4 + 0];
            float b1 = Bs[kk][tx * 4 + 1];
            float b2 = Bs[kk][tx * 4 + 2];
            float b3 = Bs[kk][tx * 4 + 3];
            acc[0][0] += a0 * b0; acc[0][1] += a0 * b1; acc[0][2] += a0 * b2; acc[0][3] += a0 * b3;
            acc[1][0] += a1 * b0; acc[1][1] += a1 * b1; acc[1][2] += a1 * b2; acc[1][3] += a1 * b3;
            acc[2][0] += a2 * b0; acc[2][1] += a2 * b1; acc[2][2] += a2 * b2; acc[2][3] += a2 * b3;
            acc[3][0] += a3 * b0; acc[3][1] += a3 * b1; acc[3][2] += a3 * b2; acc[3][3] += a3 * b3;
        }
        __syncthreads();
    }

#pragma unroll
    for (int i = 0; i < 4; ++i) {
        const int ql = qt * 64 + ty * 4 + i;   // local q row
        float* Srow = S + ((size_t)bh * QC + ql) * NTOK;
#pragma unroll
        for (int j = 0; j < 4; ++j) {
            const int k = kt * 64 + tx * 4 + j;
            Srow[k] = acc[i][j] * 0.125f;
        }
    }
}

// ---------------------------------------------------------------------------
// select_chunk: per (b, q0+ql): read precomputed S rows (coalesced), top-32
// extraction, softmax, AV, attn-mean. grid = (QC, BATCH); wave w handles
// heads w, 4+w, 8+w, 12+w.
// ---------------------------------------------------------------------------
__global__ __launch_bounds__(256) void select_chunk(const float* __restrict__ S,
                                                    const float* __restrict__ V,
                                                    float* __restrict__ ctx,
                                                    float* __restrict__ attn_out,
                                                    int q0, int QC)
{
    const int ql = blockIdx.x;
    const int b  = blockIdx.y;
    const int q  = q0 + ql;
    const int tid = threadIdx.x;
    const int wave = tid >> 6;
    const int lane = tid & 63;

    __shared__ float sc[4][NTOK];
    __shared__ float am[NTOK];
    __shared__ float selv[4][KSEL];
    __shared__ int   seli[4][KSEL];
    __shared__ float selw[4][KSEL];

    for (int j = tid; j < NTOK; j += 256) am[j] = 0.f;
    __syncthreads();

    const int L = q + 1;
    const int nsel = (L < KSEL) ? L : KSEL;

    for (int hg = 0; hg < 4; ++hg) {
        const int h = hg * 4 + wave;
        const size_t bh = (size_t)(b * HEADS + h);
        const float* Srow = S + (bh * QC + ql) * NTOK;
        const float* Vb = V + bh * NTOK * DHEAD;

        // coalesced read of the precomputed score row
        float lm = -INFINITY; int li = -1;
        for (int j = lane; j < L; j += 64) {
            const float s = Srow[j];
            sc[wave][j] = s;
            if (s > lm) { lm = s; li = j; }
        }

        // iterative top-nsel extraction (wave-synchronous)
        for (int it = 0; it < nsel; ++it) {
            float bmv = lm; int bi = li;
#pragma unroll
            for (int mask = 1; mask < 64; mask <<= 1) {
                const float ov = __shfl_xor(bmv, mask, 64);
                const int   oi = __shfl_xor(bi, mask, 64);
                if (ov > bmv || (ov == bmv && (unsigned)oi < (unsigned)bi)) {
                    bmv = ov; bi = oi;
                }
            }
            if (lane == (bi & 63)) {
                sc[wave][bi] = -INFINITY;
                lm = -INFINITY; li = -1;
                for (int j = lane; j < L; j += 64) {
                    const float s = sc[wave][j];
                    if (s > lm) { lm = s; li = j; }
                }
            }
            if (lane == 0) { selv[wave][it] = bmv; seli[wave][it] = bi; }
        }

        // softmax over selected
        const float m = selv[wave][0];
        float e = 0.f;
        if (lane < nsel) e = expf(selv[wave][lane] - m);
        float Z = e;
#pragma unroll
        for (int mask = 1; mask < 32; mask <<= 1) Z += __shfl_xor(Z, mask, 64);
        if (lane < nsel) {
            const float w = e / Z;
            selw[wave][lane] = w;
            atomicAdd(&am[seli[wave][lane]], w);
        }

        // ctx[b,q,h,:] = sum_i w_i * V[idx_i,:]   (lane = d)
        float acc = 0.f;
        for (int i = 0; i < nsel; ++i) {
            const int idx = seli[wave][i];
            const float w = selw[wave][i];
            acc += w * Vb[(size_t)idx * DHEAD + lane];
        }
        ctx[(((size_t)(b * NTOK + q)) * HEADS + h) * DHEAD + lane] = acc;
    }

    __syncthreads();
    const float invH = 1.0f / (float)HEADS;
    float* arow = attn_out + ((size_t)(b * NTOK + q)) * NTOK;
    for (int j = tid; j < NTOK; j += 256) arow[j] = am[j] * invH;
}

// ---------------------------------------------------------------------------
// Fallback fused attention (round-1 kernel) — used only if ws is too small
// even for a QC=64 score chunk.
// ---------------------------------------------------------------------------
__global__ __launch_bounds__(256) void attn_kernel(const float* __restrict__ Q,
                                                   const float* __restrict__ K,
                                                   const float* __restrict__ V,
                                                   float* __restrict__ ctx,
                                                   float* __restrict__ attn_out)
{
    const int blk = blockIdx.x;
    const int b = blk >> 11;
    const int q = blk & (NTOK - 1);
    const int tid = threadIdx.x;
    const int wave = tid >> 6;
    const int lane = tid & 63;

    __shared__ float sc[4][NTOK];
    __shared__ float am[NTOK];
    __shared__ float selv[4][KSEL];
    __shared__ int   seli[4][KSEL];
    __shared__ float selw[4][KSEL];

    for (int j = tid; j < NTOK; j += 256) am[j] = 0.f;
    __syncthreads();

    const int L = q + 1;
    const int nsel = (L < KSEL) ? L : KSEL;

    for (int hg = 0; hg < 4; ++hg) {
        const int h = hg * 4 + wave;
        const size_t bh = (size_t)(b * HEADS + h);
        const float* Qrow = Q + (bh * NTOK + q) * DHEAD;
        const float* Kb = K + bh * NTOK * DHEAD;
        const float* Vb = V + bh * NTOK * DHEAD;

        float4 qr[16];
#pragma unroll
        for (int d4 = 0; d4 < 16; ++d4) qr[d4] = ((const float4*)Qrow)[d4];

        float lm = -INFINITY; int li = -1;
        for (int j = lane; j < L; j += 64) {
            const float4* kr = (const float4*)(Kb + (size_t)j * DHEAD);
            float a0 = 0.f, a1 = 0.f, a2 = 0.f, a3 = 0.f;
#pragma unroll
            for (int d4 = 0; d4 < 16; ++d4) {
                const float4 kk = kr[d4];
                a0 += qr[d4].x * kk.x;
                a1 += qr[d4].y * kk.y;
                a2 += qr[d4].z * kk.z;
                a3 += qr[d4].w * kk.w;
            }
            const float s = (a0 + a1 + a2 + a3) * 0.125f;
            sc[wave][j] = s;
            if (s > lm) { lm = s; li = j; }
        }

        for (int it = 0; it < nsel; ++it) {
            float bmv = lm; int bi = li;
#pragma unroll
            for (int mask = 1; mask < 64; mask <<= 1) {
                const float ov = __shfl_xor(bmv, mask, 64);
                const int   oi = __shfl_xor(bi, mask, 64);
                if (ov > bmv || (ov == bmv && (unsigned)oi < (unsigned)bi)) {
                    bmv = ov; bi = oi;
                }
            }
            if (lane == (bi & 63)) {
                sc[wave][bi] = -INFINITY;
                lm = -INFINITY; li = -1;
                for (int j = lane; j < L; j += 64) {
                    const float s = sc[wave][j];
                    if (s > lm) { lm = s; li = j; }
                }
            }
            if (lane == 0) { selv[wave][it] = bmv; seli[wave][it] = bi; }
        }

        const float m = selv[wave][0];
        float e = 0.f;
        if (lane < nsel) e = expf(selv[wave][lane] - m);
        float Z = e;
#pragma unroll
        for (int mask = 1; mask < 32; mask <<= 1) Z += __shfl_xor(Z, mask, 64);
        if (lane < nsel) {
            const float w = e / Z;
            selw[wave][lane] = w;
            atomicAdd(&am[seli[wave][lane]], w);
        }

        float acc = 0.f;
        for (int i = 0; i < nsel; ++i) {
            const int idx = seli[wave][i];
            const float w = selw[wave][i];
            acc += w * Vb[(size_t)idx * DHEAD + lane];
        }
        ctx[(((size_t)(b * NTOK + q)) * HEADS + h) * DHEAD + lane] = acc;
    }

    __syncthreads();
    const float invH = 1.0f / (float)HEADS;
    float* arow = attn_out + ((size_t)(b * NTOK + q)) * NTOK;
    for (int j = tid; j < NTOK; j += 256) arow[j] = am[j] * invH;
}

// ---------------------------------------------------------------------------
extern "C" void kernel_launch(void* const* d_in, const int* in_sizes, int n_in,
                              void* d_out, int out_size, void* d_ws, size_t ws_size,
                              hipStream_t stream) {
    const float* x  = (const float*)d_in[0];
    const float* Wq = (const float*)d_in[1];
    const float* bq = (const float*)d_in[2];
    const float* Wk = (const float*)d_in[3];
    const float* bk = (const float*)d_in[4];
    const float* Wv = (const float*)d_in[5];
    const float* bv = (const float*)d_in[6];
    const float* Wo = (const float*)d_in[7];
    const float* bo = (const float*)d_in[8];

    const size_t SZ = (size_t)MROWS * DMODEL;  // 4,194,304 floats
    float* ws  = (float*)d_ws;
    float* Qws = ws;
    float* Kws = ws + SZ;
    float* Vws = ws + 2 * SZ;
    float* ctx = ws + 3 * SZ;
    float* Sws = ws + 4 * SZ;   // score chunk buffer [32 bh][QC][2048] fp32

    float* y    = (float*)d_out;
    float* attn = y + (size_t)BATCH * NTOK * DMODEL;

    dim3 gemm_grid(MROWS / 64, DMODEL / 64);
    gemm_nt<<<gemm_grid, 256, 0, stream>>>(x, Wq, bq, Qws, 1);
    gemm_nt<<<gemm_grid, 256, 0, stream>>>(x, Wk, bk, Kws, 1);
    gemm_nt<<<gemm_grid, 256, 0, stream>>>(x, Wv, bv, Vws, 1);

    // pick the largest power-of-two q-chunk whose score buffer fits in ws
    const size_t ws_floats = ws_size / sizeof(float);
    const size_t base_floats = 4 * SZ;
    const size_t avail = (ws_floats > base_floats) ? ws_floats - base_floats : 0;
    int QC = 0;
    for (int cand = NTOK; cand >= 64; cand >>= 1) {
        const size_t need = (size_t)BATCH * HEADS * cand * NTOK;  // floats
        if (need <= avail) { QC = cand; break; }
    }

    if (QC > 0) {
        for (int q0 = 0; q0 < NTOK; q0 += QC) {
            dim3 sgrid((q0 + QC) / 64, QC / 64, BATCH * HEADS);
            score_chunk<<<sgrid, 256, 0, stream>>>(Qws, Kws, Sws, q0, QC);
            dim3 selgrid(QC, BATCH);
            select_chunk<<<selgrid, 256, 0, stream>>>(Sws, Vws, ctx, attn, q0, QC);
        }
    } else {
        attn_kernel<<<BATCH * NTOK, 256, 0, stream>>>(Qws, Kws, Vws, ctx, attn);
    }

    gemm_nt<<<gemm_grid, 256, 0, stream>>>(ctx, Wo, bo, y, 0);
}

// Round 4
// 1609.453 us; speedup vs baseline: 2.0431x; 1.8155x over previous
//
#include <hip/hip_runtime.h>
#include <hip/hip_bf16.h>
#include <math.h>

// Problem constants
#define BATCH   2
#define NTOK    2048
#define DMODEL  1024
#define HEADS   16
#define DHEAD   64
#define KSEL    32
#define MROWS   (BATCH * NTOK)   // 4096

// ---------------------------------------------------------------------------
// GEMM: C[m,o] = sum_k A[m,k] * W[o,k] + bias[o]
// ---------------------------------------------------------------------------
__global__ __launch_bounds__(256) void gemm_nt(const float* __restrict__ A,
                                               const float* __restrict__ W,
                                               const float* __restrict__ bias,
                                               float* __restrict__ out,
                                               int scatter)
{
    __shared__ float As[16][65];  // As[k][m]
    __shared__ float Bs[16][65];  // Bs[k][o]

    const int tid = threadIdx.x;
    const int bm = blockIdx.x * 64;
    const int bo = blockIdx.y * 64;
    const int tx = tid & 15;
    const int ty = tid >> 4;

    const int lr = tid >> 2;
    const int lc = (tid & 3) << 2;

    float acc[4][4];
#pragma unroll
    for (int i = 0; i < 4; ++i)
#pragma unroll
        for (int j = 0; j < 4; ++j) acc[i][j] = 0.f;

    for (int k0 = 0; k0 < DMODEL; k0 += 16) {
        float4 av = *(const float4*)(A + (size_t)(bm + lr) * DMODEL + k0 + lc);
        float4 bv = *(const float4*)(W + (size_t)(bo + lr) * DMODEL + k0 + lc);
        As[lc + 0][lr] = av.x; As[lc + 1][lr] = av.y;
        As[lc + 2][lr] = av.z; As[lc + 3][lr] = av.w;
        Bs[lc + 0][lr] = bv.x; Bs[lc + 1][lr] = bv.y;
        Bs[lc + 2][lr] = bv.z; Bs[lc + 3][lr] = bv.w;
        __syncthreads();
#pragma unroll
        for (int kk = 0; kk < 16; ++kk) {
            float a0 = As[kk][ty * 4 + 0];
            float a1 = As[kk][ty * 4 + 1];
            float a2 = As[kk][ty * 4 + 2];
            float a3 = As[kk][ty * 4 + 3];
            float b0 = Bs[kk][tx * 4 + 0];
            float b1 = Bs[kk][tx * 4 + 1];
            float b2 = Bs[kk][tx * 4 + 2];
            float b3 = Bs[kk][tx * 4 + 3];
            acc[0][0] += a0 * b0; acc[0][1] += a0 * b1; acc[0][2] += a0 * b2; acc[0][3] += a0 * b3;
            acc[1][0] += a1 * b0; acc[1][1] += a1 * b1; acc[1][2] += a1 * b2; acc[1][3] += a1 * b3;
            acc[2][0] += a2 * b0; acc[2][1] += a2 * b1; acc[2][2] += a2 * b2; acc[2][3] += a2 * b3;
            acc[3][0] += a3 * b0; acc[3][1] += a3 * b1; acc[3][2] += a3 * b2; acc[3][3] += a3 * b3;
        }
        __syncthreads();
    }

#pragma unroll
    for (int i = 0; i < 4; ++i) {
        const int m = bm + ty * 4 + i;
#pragma unroll
        for (int j = 0; j < 4; ++j) {
            const int o = bo + tx * 4 + j;
            const float v = acc[i][j] + bias[o];
            if (scatter) {
                const int bb = m >> 11;
                const int n  = m & 2047;
                const int h  = o >> 6;
                const int d  = o & 63;
                out[(((size_t)(bb * HEADS + h)) * NTOK + n) * DHEAD + d] = v;
            } else {
                out[(size_t)m * DMODEL + o] = v;
            }
        }
    }
}

// ---------------------------------------------------------------------------
// score_chunk: S[bh, q_local, k] = (Q[bh, q0+q_local, :] . K[bh, k, :]) / 8
// ---------------------------------------------------------------------------
__global__ __launch_bounds__(256) void score_chunk(const float* __restrict__ Q,
                                                   const float* __restrict__ K,
                                                   float* __restrict__ S,
                                                   int q0, int QC)
{
    const int kt = blockIdx.x;
    const int qt = blockIdx.y;
    const int qt_g = (q0 >> 6) + qt;
    if (kt > qt_g) return;
    const int bh = blockIdx.z;

    __shared__ float As[16][65];
    __shared__ float Bs[16][65];

    const int tid = threadIdx.x;
    const int tx = tid & 15;
    const int ty = tid >> 4;
    const int lr = tid >> 2;
    const int lc = (tid & 3) << 2;

    const float* Qb = Q + ((size_t)bh * NTOK + q0 + qt * 64) * DHEAD;
    const float* Kb = K + ((size_t)bh * NTOK + kt * 64) * DHEAD;

    float acc[4][4];
#pragma unroll
    for (int i = 0; i < 4; ++i)
#pragma unroll
        for (int j = 0; j < 4; ++j) acc[i][j] = 0.f;

#pragma unroll
    for (int k0 = 0; k0 < DHEAD; k0 += 16) {
        float4 av = *(const float4*)(Qb + (size_t)lr * DHEAD + k0 + lc);
        float4 bv = *(const float4*)(Kb + (size_t)lr * DHEAD + k0 + lc);
        As[lc + 0][lr] = av.x; As[lc + 1][lr] = av.y;
        As[lc + 2][lr] = av.z; As[lc + 3][lr] = av.w;
        Bs[lc + 0][lr] = bv.x; Bs[lc + 1][lr] = bv.y;
        Bs[lc + 2][lr] = bv.z; Bs[lc + 3][lr] = bv.w;
        __syncthreads();
#pragma unroll
        for (int kk = 0; kk < 16; ++kk) {
            float a0 = As[kk][ty * 4 + 0];
            float a1 = As[kk][ty * 4 + 1];
            float a2 = As[kk][ty * 4 + 2];
            float a3 = As[kk][ty * 4 + 3];
            float b0 = Bs[kk][tx * 4 + 0];
            float b1 = Bs[kk][tx * 4 + 1];
            float b2 = Bs[kk][tx * 4 + 2];
            float b3 = Bs[kk][tx * 4 + 3];
            acc[0][0] += a0 * b0; acc[0][1] += a0 * b1; acc[0][2] += a0 * b2; acc[0][3] += a0 * b3;
            acc[1][0] += a1 * b0; acc[1][1] += a1 * b1; acc[1][2] += a1 * b2; acc[1][3] += a1 * b3;
            acc[2][0] += a2 * b0; acc[2][1] += a2 * b1; acc[2][2] += a2 * b2; acc[2][3] += a2 * b3;
            acc[3][0] += a3 * b0; acc[3][1] += a3 * b1; acc[3][2] += a3 * b2; acc[3][3] += a3 * b3;
        }
        __syncthreads();
    }

#pragma unroll
    for (int i = 0; i < 4; ++i) {
        const int ql = qt * 64 + ty * 4 + i;
        float* Srow = S + ((size_t)bh * QC + ql) * NTOK;
#pragma unroll
        for (int j = 0; j < 4; ++j) {
            const int k = kt * 64 + tx * 4 + j;
            Srow[k] = acc[i][j] * 0.125f;
        }
    }
}

// ---------------------------------------------------------------------------
// select_chunk v2: register-resident scores, per-lane top-2 cache, O(1) pop,
// rare register-rescan refill. One wave per (q,h-group); wave handles heads
// wave, 4+wave, 8+wave, 12+wave serially. grid = (QC, BATCH).
// ---------------------------------------------------------------------------
__global__ __launch_bounds__(256) void select_chunk(const float* __restrict__ S,
                                                    const float* __restrict__ V,
                                                    float* __restrict__ ctx,
                                                    float* __restrict__ attn_out,
                                                    int q0, int QC)
{
    const int ql = blockIdx.x;
    const int b  = blockIdx.y;
    const int q  = q0 + ql;
    const int tid = threadIdx.x;
    const int wave = tid >> 6;
    const int lane = tid & 63;

    __shared__ float am[NTOK];          // attn-mean accumulator (8 KB)
    __shared__ float selw[4][KSEL];
    __shared__ int   selidx[4][KSEL];

    for (int j = tid; j < NTOK; j += 256) am[j] = 0.f;
    __syncthreads();

    const int L = q + 1;
    const int nsel = (L < KSEL) ? L : KSEL;

    for (int hg = 0; hg < 4; ++hg) {
        const int h = hg * 4 + wave;
        const size_t bh = (size_t)(b * HEADS + h);
        const float* Srow = S + (bh * QC + ql) * NTOK;
        const float* Vb = V + bh * NTOK * DHEAD;

        // ---- load row into registers: slot s holds global index j = s*64+lane
        float r[32];
        int valid = 0;
#pragma unroll
        for (int s = 0; s < 32; ++s) {
            const int j = s * 64 + lane;
            float v = -INFINITY;
            if (j < L) { v = Srow[j]; ++valid; }
            r[s] = v;
        }

        // ---- per-lane top-2 cache, ordered (value desc, index asc)
        float v1 = -INFINITY, v2 = -INFINITY;
        int   i1 = 0x7FFFFFFF, i2 = 0x7FFFFFFF;
#pragma unroll
        for (int s = 0; s < 32; ++s) {
            const float v = r[s];
            const int j = s * 64 + lane;
            if (v > v1)      { v2 = v1; i2 = i1; v1 = v; i1 = j; }
            else if (v > v2) { v2 = v; i2 = j; }
        }
        int incache = (valid >= 2) ? 2 : valid;
        int rem = valid - incache;
        unsigned taken = 0u;

        float m = 0.f;
        float selv_r = 0.f;
        int   seli_r = 0;

        for (int it = 0; it < nsel; ++it) {
            // wave max over cache heads
            float bmv = v1;
#pragma unroll
            for (int mask = 1; mask < 64; mask <<= 1) {
                const float ov = __shfl_xor(bmv, mask, 64);
                bmv = (ov > bmv) ? ov : bmv;
            }
            // smallest global index among lanes achieving the max
            int cand = (v1 == bmv) ? i1 : 0x7FFFFFFF;
#pragma unroll
            for (int mask = 1; mask < 64; mask <<= 1) {
                const int oi = __shfl_xor(cand, mask, 64);
                cand = (oi < cand) ? oi : cand;
            }
            const int gidx = cand;
            if (it == 0) m = bmv;                       // uniform
            if (lane == it) { selv_r = bmv; seli_r = gidx; }

            // owning lane pops its cache head (== extracted element)
            if (lane == (gidx & 63)) {
                taken |= (1u << (gidx >> 6));
                v1 = v2; i1 = i2;
                v2 = -INFINITY; i2 = 0x7FFFFFFF;
                --incache;
                if (incache == 0 && rem > 0) {
                    // rare refill: rebuild top-2 among untaken, from registers
                    v1 = -INFINITY; i1 = 0x7FFFFFFF;
#pragma unroll
                    for (int s = 0; s < 32; ++s) {
                        if (taken & (1u << s)) continue;
                        const float v = r[s];
                        const int j = s * 64 + lane;
                        if (v > v1)      { v2 = v1; i2 = i1; v1 = v; i1 = j; }
                        else if (v > v2) { v2 = v; i2 = j; }
                    }
                    incache = (rem >= 2) ? 2 : rem;
                    rem -= incache;
                }
            }
        }

        // ---- softmax over selected (lane i holds extraction i)
        float e = 0.f;
        if (lane < nsel) e = __expf(selv_r - m);
        float Z = e;
#pragma unroll
        for (int mask = 1; mask < 32; mask <<= 1) Z += __shfl_xor(Z, mask, 64);
        if (lane < nsel) {
            const float w = e / Z;
            selw[wave][lane] = w;
            selidx[wave][lane] = seli_r;
            atomicAdd(&am[seli_r], w);
        }

        // ---- ctx[b,q,h,:] = sum_i w_i * V[idx_i,:]   (lane = d)
        float acc = 0.f;
        for (int i = 0; i < nsel; ++i) {
            const int idx = selidx[wave][i];
            const float ww = selw[wave][i];
            acc += ww * Vb[(size_t)idx * DHEAD + lane];
        }
        ctx[(((size_t)(b * NTOK + q)) * HEADS + h) * DHEAD + lane] = acc;
    }

    __syncthreads();
    const float invH = 1.0f / (float)HEADS;
    float* arow = attn_out + ((size_t)(b * NTOK + q)) * NTOK;
    for (int j = tid; j < NTOK; j += 256) arow[j] = am[j] * invH;
}

// ---------------------------------------------------------------------------
// Fallback fused attention (round-1 kernel) — only if ws can't fit QC=64.
// ---------------------------------------------------------------------------
__global__ __launch_bounds__(256) void attn_kernel(const float* __restrict__ Q,
                                                   const float* __restrict__ K,
                                                   const float* __restrict__ V,
                                                   float* __restrict__ ctx,
                                                   float* __restrict__ attn_out)
{
    const int blk = blockIdx.x;
    const int b = blk >> 11;
    const int q = blk & (NTOK - 1);
    const int tid = threadIdx.x;
    const int wave = tid >> 6;
    const int lane = tid & 63;

    __shared__ float sc[4][NTOK];
    __shared__ float am[NTOK];
    __shared__ float selv[4][KSEL];
    __shared__ int   seli[4][KSEL];
    __shared__ float selw[4][KSEL];

    for (int j = tid; j < NTOK; j += 256) am[j] = 0.f;
    __syncthreads();

    const int L = q + 1;
    const int nsel = (L < KSEL) ? L : KSEL;

    for (int hg = 0; hg < 4; ++hg) {
        const int h = hg * 4 + wave;
        const size_t bh = (size_t)(b * HEADS + h);
        const float* Qrow = Q + (bh * NTOK + q) * DHEAD;
        const float* Kb = K + bh * NTOK * DHEAD;
        const float* Vb = V + bh * NTOK * DHEAD;

        float4 qr[16];
#pragma unroll
        for (int d4 = 0; d4 < 16; ++d4) qr[d4] = ((const float4*)Qrow)[d4];

        float lm = -INFINITY; int li = -1;
        for (int j = lane; j < L; j += 64) {
            const float4* kr = (const float4*)(Kb + (size_t)j * DHEAD);
            float a0 = 0.f, a1 = 0.f, a2 = 0.f, a3 = 0.f;
#pragma unroll
            for (int d4 = 0; d4 < 16; ++d4) {
                const float4 kk = kr[d4];
                a0 += qr[d4].x * kk.x;
                a1 += qr[d4].y * kk.y;
                a2 += qr[d4].z * kk.z;
                a3 += qr[d4].w * kk.w;
            }
            const float s = (a0 + a1 + a2 + a3) * 0.125f;
            sc[wave][j] = s;
            if (s > lm) { lm = s; li = j; }
        }

        for (int it = 0; it < nsel; ++it) {
            float bmv = lm; int bi = li;
#pragma unroll
            for (int mask = 1; mask < 64; mask <<= 1) {
                const float ov = __shfl_xor(bmv, mask, 64);
                const int   oi = __shfl_xor(bi, mask, 64);
                if (ov > bmv || (ov == bmv && (unsigned)oi < (unsigned)bi)) {
                    bmv = ov; bi = oi;
                }
            }
            if (lane == (bi & 63)) {
                sc[wave][bi] = -INFINITY;
                lm = -INFINITY; li = -1;
                for (int j = lane; j < L; j += 64) {
                    const float s = sc[wave][j];
                    if (s > lm) { lm = s; li = j; }
                }
            }
            if (lane == 0) { selv[wave][it] = bmv; seli[wave][it] = bi; }
        }

        const float m = selv[wave][0];
        float e = 0.f;
        if (lane < nsel) e = expf(selv[wave][lane] - m);
        float Z = e;
#pragma unroll
        for (int mask = 1; mask < 32; mask <<= 1) Z += __shfl_xor(Z, mask, 64);
        if (lane < nsel) {
            const float w = e / Z;
            selw[wave][lane] = w;
            atomicAdd(&am[seli[wave][lane]], w);
        }

        float acc = 0.f;
        for (int i = 0; i < nsel; ++i) {
            const int idx = seli[wave][i];
            const float w = selw[wave][i];
            acc += w * Vb[(size_t)idx * DHEAD + lane];
        }
        ctx[(((size_t)(b * NTOK + q)) * HEADS + h) * DHEAD + lane] = acc;
    }

    __syncthreads();
    const float invH = 1.0f / (float)HEADS;
    float* arow = attn_out + ((size_t)(b * NTOK + q)) * NTOK;
    for (int j = tid; j < NTOK; j += 256) arow[j] = am[j] * invH;
}

// ---------------------------------------------------------------------------
extern "C" void kernel_launch(void* const* d_in, const int* in_sizes, int n_in,
                              void* d_out, int out_size, void* d_ws, size_t ws_size,
                              hipStream_t stream) {
    const float* x  = (const float*)d_in[0];
    const float* Wq = (const float*)d_in[1];
    const float* bq = (const float*)d_in[2];
    const float* Wk = (const float*)d_in[3];
    const float* bk = (const float*)d_in[4];
    const float* Wv = (const float*)d_in[5];
    const float* bv = (const float*)d_in[6];
    const float* Wo = (const float*)d_in[7];
    const float* bo = (const float*)d_in[8];

    const size_t SZ = (size_t)MROWS * DMODEL;  // 4,194,304 floats
    float* ws  = (float*)d_ws;
    float* Qws = ws;
    float* Kws = ws + SZ;
    float* Vws = ws + 2 * SZ;
    float* ctx = ws + 3 * SZ;
    float* Sws = ws + 4 * SZ;   // score chunk buffer [32 bh][QC][2048] fp32

    float* y    = (float*)d_out;
    float* attn = y + (size_t)BATCH * NTOK * DMODEL;

    dim3 gemm_grid(MROWS / 64, DMODEL / 64);
    gemm_nt<<<gemm_grid, 256, 0, stream>>>(x, Wq, bq, Qws, 1);
    gemm_nt<<<gemm_grid, 256, 0, stream>>>(x, Wk, bk, Kws, 1);
    gemm_nt<<<gemm_grid, 256, 0, stream>>>(x, Wv, bv, Vws, 1);

    // largest power-of-two q-chunk whose score buffer fits in ws
    const size_t ws_floats = ws_size / sizeof(float);
    const size_t base_floats = 4 * SZ;
    const size_t avail = (ws_floats > base_floats) ? ws_floats - base_floats : 0;
    int QC = 0;
    for (int cand = NTOK; cand >= 64; cand >>= 1) {
        const size_t need = (size_t)BATCH * HEADS * cand * NTOK;  // floats
        if (need <= avail) { QC = cand; break; }
    }

    if (QC > 0) {
        for (int q0 = 0; q0 < NTOK; q0 += QC) {
            dim3 sgrid((q0 + QC) / 64, QC / 64, BATCH * HEADS);
            score_chunk<<<sgrid, 256, 0, stream>>>(Qws, Kws, Sws, q0, QC);
            dim3 selgrid(QC, BATCH);
            select_chunk<<<selgrid, 256, 0, stream>>>(Sws, Vws, ctx, attn, q0, QC);
        }
    } else {
        attn_kernel<<<BATCH * NTOK, 256, 0, stream>>>(Qws, Kws, Vws, ctx, attn);
    }

    gemm_nt<<<gemm_grid, 256, 0, stream>>>(ctx, Wo, bo, y, 0);
}

// Round 6
// 1083.733 us; speedup vs baseline: 3.0342x; 1.4851x over previous
//
#include <hip/hip_runtime.h>
#include <hip/hip_bf16.h>
#include <math.h>

// Problem constants
#define BATCH   2
#define NTOK    2048
#define DMODEL  1024
#define HEADS   16
#define DHEAD   64
#define KSEL    32
#define MROWS   (BATCH * NTOK)   // 4096

typedef short     bf16x8 __attribute__((ext_vector_type(8)));
typedef float     f32x4  __attribute__((ext_vector_type(4)));
typedef unsigned short ushort_t;

#define GLOAD_LDS16(g, l) \
    __builtin_amdgcn_global_load_lds((const __attribute__((address_space(1))) void*)(g), \
                                     (__attribute__((address_space(3))) void*)(l), 16, 0, 0)

// ---------------------------------------------------------------------------
// f32 -> (hi, lo) bf16 split: hi = bf16(x), lo = bf16(x - hi)
// ---------------------------------------------------------------------------
__device__ __forceinline__ ushort_t f2bf(float f) {
    unsigned u = __float_as_uint(f);
    unsigned r = (u + 0x7FFFu + ((u >> 16) & 1u)) >> 16;
    return (ushort_t)r;
}
__device__ __forceinline__ float bf2f(ushort_t h) {
    return __uint_as_float(((unsigned)h) << 16);
}

__global__ __launch_bounds__(256) void conv_split(const float* __restrict__ in,
                                                  ushort_t* __restrict__ hi,
                                                  ushort_t* __restrict__ lo, int n)
{
    const int i = (blockIdx.x * 256 + threadIdx.x) * 4;
    if (i + 3 < n) {
        const float4 v = *(const float4*)(in + i);
        ushort4 ph, pl;
        ph.x = f2bf(v.x); pl.x = f2bf(v.x - bf2f(ph.x));
        ph.y = f2bf(v.y); pl.y = f2bf(v.y - bf2f(ph.y));
        ph.z = f2bf(v.z); pl.z = f2bf(v.z - bf2f(ph.z));
        ph.w = f2bf(v.w); pl.w = f2bf(v.w - bf2f(ph.w));
        *(ushort4*)(hi + i) = ph;
        *(ushort4*)(lo + i) = pl;
    }
}

// ---------------------------------------------------------------------------
// Split-bf16 MFMA GEMM: C = A*B^T + bias, A=[M,1024], B=[1024(out),1024(k)]
//   A ~ Ahi+Alo, B ~ Bhi+Blo; C ≈ Ahi·Bhi + Ahi·Blo + Alo·Bhi  (fp32 acc)
//   tile M=128, N=64, BK=32; 256 threads / 4 waves; wave owns 32 M-rows.
//   scatter==1: out as [b,h,n,d] (b=m>>11, n=m&2047, h=o>>6, d=o&63)
// ---------------------------------------------------------------------------
__global__ __launch_bounds__(256) void gemm_split_mfma(const ushort_t* __restrict__ Ahi,
                                                       const ushort_t* __restrict__ Alo,
                                                       const ushort_t* __restrict__ Bhi,
                                                       const ushort_t* __restrict__ Blo,
                                                       const float* __restrict__ bias,
                                                       float* __restrict__ out,
                                                       int scatter)
{
    __shared__ ushort_t AbufH[128 * 32];   // 8 KB
    __shared__ ushort_t AbufL[128 * 32];   // 8 KB
    __shared__ ushort_t BbufH[64 * 32];    // 4 KB
    __shared__ ushort_t BbufL[64 * 32];    // 4 KB

    const int tid  = threadIdx.x;
    const int wave = tid >> 6;
    const int lane = tid & 63;
    const int m0 = blockIdx.x * 128;
    const int n0 = blockIdx.y * 64;

    f32x4 acc[2][4];
#pragma unroll
    for (int i = 0; i < 2; ++i)
#pragma unroll
        for (int j = 0; j < 4; ++j) acc[i][j] = (f32x4){0.f, 0.f, 0.f, 0.f};

    const int ar0 = tid >> 2;              // A rows 0..63
    const int ar1 = 64 + (tid >> 2);       // A rows 64..127
    const int ak  = (tid & 3) << 3;        // k offset (elems)
    const int br  = tid >> 2;              // B rows 0..63

    const int fr = lane & 15;              // fragment row
    const int fk = (lane >> 4) << 3;       // fragment k offset

    for (int k0 = 0; k0 < DMODEL; k0 += 32) {
        __syncthreads();
        const size_t aoff0 = (size_t)(m0 + ar0) * DMODEL + k0 + ak;
        const size_t aoff1 = (size_t)(m0 + ar1) * DMODEL + k0 + ak;
        const size_t boff  = (size_t)(n0 + br) * DMODEL + k0 + ak;
        GLOAD_LDS16(Ahi + aoff0, AbufH + (size_t)tid * 8);
        GLOAD_LDS16(Ahi + aoff1, AbufH + (size_t)(256 + tid) * 8);
        GLOAD_LDS16(Alo + aoff0, AbufL + (size_t)tid * 8);
        GLOAD_LDS16(Alo + aoff1, AbufL + (size_t)(256 + tid) * 8);
        GLOAD_LDS16(Bhi + boff, BbufH + (size_t)tid * 8);
        GLOAD_LDS16(Blo + boff, BbufL + (size_t)tid * 8);
        __syncthreads();

        bf16x8 afh[2], afl[2], bfh[4], bfl[4];
#pragma unroll
        for (int mi = 0; mi < 2; ++mi) {
            const int ro = (wave * 32 + mi * 16 + fr) * 32 + fk;
            afh[mi] = *(const bf16x8*)(AbufH + ro);
            afl[mi] = *(const bf16x8*)(AbufL + ro);
        }
#pragma unroll
        for (int ni = 0; ni < 4; ++ni) {
            const int ro = (ni * 16 + fr) * 32 + fk;
            bfh[ni] = *(const bf16x8*)(BbufH + ro);
            bfl[ni] = *(const bf16x8*)(BbufL + ro);
        }

#pragma unroll
        for (int mi = 0; mi < 2; ++mi)
#pragma unroll
            for (int ni = 0; ni < 4; ++ni) {
                acc[mi][ni] = __builtin_amdgcn_mfma_f32_16x16x32_bf16(afh[mi], bfl[ni], acc[mi][ni], 0, 0, 0);
                acc[mi][ni] = __builtin_amdgcn_mfma_f32_16x16x32_bf16(afl[mi], bfh[ni], acc[mi][ni], 0, 0, 0);
                acc[mi][ni] = __builtin_amdgcn_mfma_f32_16x16x32_bf16(afh[mi], bfh[ni], acc[mi][ni], 0, 0, 0);
            }
    }

    // epilogue: C/D layout col=lane&15, row=(lane>>4)*4+reg
#pragma unroll
    for (int ni = 0; ni < 4; ++ni) {
        const int o = n0 + ni * 16 + (lane & 15);
        const float bv = bias[o];
#pragma unroll
        for (int mi = 0; mi < 2; ++mi) {
#pragma unroll
            for (int reg = 0; reg < 4; ++reg) {
                const int m = m0 + wave * 32 + mi * 16 + ((lane >> 4) << 2) + reg;
                const float v = acc[mi][ni][reg] + bv;
                if (scatter) {
                    const int bb = m >> 11;
                    const int n  = m & 2047;
                    const int h  = o >> 6;
                    const int d  = o & 63;
                    out[(((size_t)(bb * HEADS + h)) * NTOK + n) * DHEAD + d] = v;
                } else {
                    out[(size_t)m * DMODEL + o] = v;
                }
            }
        }
    }
}

// ---------------------------------------------------------------------------
// score_chunk: S[bh, q_local, k] = (Q[bh, q0+q_local, :] . K[bh, k, :]) / 8
// ---------------------------------------------------------------------------
__global__ __launch_bounds__(256) void score_chunk(const float* __restrict__ Q,
                                                   const float* __restrict__ K,
                                                   float* __restrict__ S,
                                                   int q0, int QC)
{
    const int kt = blockIdx.x;
    const int qt = blockIdx.y;
    const int qt_g = (q0 >> 6) + qt;
    if (kt > qt_g) return;
    const int bh = blockIdx.z;

    __shared__ float As[16][65];
    __shared__ float Bs[16][65];

    const int tid = threadIdx.x;
    const int tx = tid & 15;
    const int ty = tid >> 4;
    const int lr = tid >> 2;
    const int lc = (tid & 3) << 2;

    const float* Qb = Q + ((size_t)bh * NTOK + q0 + qt * 64) * DHEAD;
    const float* Kb = K + ((size_t)bh * NTOK + kt * 64) * DHEAD;

    float acc[4][4];
#pragma unroll
    for (int i = 0; i < 4; ++i)
#pragma unroll
        for (int j = 0; j < 4; ++j) acc[i][j] = 0.f;

#pragma unroll
    for (int k0 = 0; k0 < DHEAD; k0 += 16) {
        float4 av = *(const float4*)(Qb + (size_t)lr * DHEAD + k0 + lc);
        float4 bv = *(const float4*)(Kb + (size_t)lr * DHEAD + k0 + lc);
        As[lc + 0][lr] = av.x; As[lc + 1][lr] = av.y;
        As[lc + 2][lr] = av.z; As[lc + 3][lr] = av.w;
        Bs[lc + 0][lr] = bv.x; Bs[lc + 1][lr] = bv.y;
        Bs[lc + 2][lr] = bv.z; Bs[lc + 3][lr] = bv.w;
        __syncthreads();
#pragma unroll
        for (int kk = 0; kk < 16; ++kk) {
            float a0 = As[kk][ty * 4 + 0];
            float a1 = As[kk][ty * 4 + 1];
            float a2 = As[kk][ty * 4 + 2];
            float a3 = As[kk][ty * 4 + 3];
            float b0 = Bs[kk][tx * 4 + 0];
            float b1 = Bs[kk][tx * 4 + 1];
            float b2 = Bs[kk][tx * 4 + 2];
            float b3 = Bs[kk][tx * 4 + 3];
            acc[0][0] += a0 * b0; acc[0][1] += a0 * b1; acc[0][2] += a0 * b2; acc[0][3] += a0 * b3;
            acc[1][0] += a1 * b0; acc[1][1] += a1 * b1; acc[1][2] += a1 * b2; acc[1][3] += a1 * b3;
            acc[2][0] += a2 * b0; acc[2][1] += a2 * b1; acc[2][2] += a2 * b2; acc[2][3] += a2 * b3;
            acc[3][0] += a3 * b0; acc[3][1] += a3 * b1; acc[3][2] += a3 * b2; acc[3][3] += a3 * b3;
        }
        __syncthreads();
    }

#pragma unroll
    for (int i = 0; i < 4; ++i) {
        const int ql = qt * 64 + ty * 4 + i;
        float* Srow = S + ((size_t)bh * QC + ql) * NTOK;
#pragma unroll
        for (int j = 0; j < 4; ++j) {
            const int k = kt * 64 + tx * 4 + j;
            Srow[k] = acc[i][j] * 0.125f;
        }
    }
}

// ---------------------------------------------------------------------------
// select_chunk v2: register-resident scores, per-lane top-2 cache, O(1) pop.
// ---------------------------------------------------------------------------
__global__ __launch_bounds__(256) void select_chunk(const float* __restrict__ S,
                                                    const float* __restrict__ V,
                                                    float* __restrict__ ctx,
                                                    float* __restrict__ attn_out,
                                                    int q0, int QC)
{
    const int ql = blockIdx.x;
    const int b  = blockIdx.y;
    const int q  = q0 + ql;
    const int tid = threadIdx.x;
    const int wave = tid >> 6;
    const int lane = tid & 63;

    __shared__ float am[NTOK];
    __shared__ float selw[4][KSEL];
    __shared__ int   selidx[4][KSEL];

    for (int j = tid; j < NTOK; j += 256) am[j] = 0.f;
    __syncthreads();

    const int L = q + 1;
    const int nsel = (L < KSEL) ? L : KSEL;

    for (int hg = 0; hg < 4; ++hg) {
        const int h = hg * 4 + wave;
        const size_t bh = (size_t)(b * HEADS + h);
        const float* Srow = S + (bh * QC + ql) * NTOK;
        const float* Vb = V + bh * NTOK * DHEAD;

        float r[32];
        int valid = 0;
#pragma unroll
        for (int s = 0; s < 32; ++s) {
            const int j = s * 64 + lane;
            float v = -INFINITY;
            if (j < L) { v = Srow[j]; ++valid; }
            r[s] = v;
        }

        float v1 = -INFINITY, v2 = -INFINITY;
        int   i1 = 0x7FFFFFFF, i2 = 0x7FFFFFFF;
#pragma unroll
        for (int s = 0; s < 32; ++s) {
            const float v = r[s];
            const int j = s * 64 + lane;
            if (v > v1)      { v2 = v1; i2 = i1; v1 = v; i1 = j; }
            else if (v > v2) { v2 = v; i2 = j; }
        }
        int incache = (valid >= 2) ? 2 : valid;
        int rem = valid - incache;
        unsigned taken = 0u;

        float m = 0.f;
        float selv_r = 0.f;
        int   seli_r = 0;

        for (int it = 0; it < nsel; ++it) {
            float bmv = v1;
#pragma unroll
            for (int mask = 1; mask < 64; mask <<= 1) {
                const float ov = __shfl_xor(bmv, mask, 64);
                bmv = (ov > bmv) ? ov : bmv;
            }
            int cand = (v1 == bmv) ? i1 : 0x7FFFFFFF;
#pragma unroll
            for (int mask = 1; mask < 64; mask <<= 1) {
                const int oi = __shfl_xor(cand, mask, 64);
                cand = (oi < cand) ? oi : cand;
            }
            const int gidx = cand;
            if (it == 0) m = bmv;
            if (lane == it) { selv_r = bmv; seli_r = gidx; }

            if (lane == (gidx & 63)) {
                taken |= (1u << (gidx >> 6));
                v1 = v2; i1 = i2;
                v2 = -INFINITY; i2 = 0x7FFFFFFF;
                --incache;
                if (incache == 0 && rem > 0) {
                    v1 = -INFINITY; i1 = 0x7FFFFFFF;
#pragma unroll
                    for (int s = 0; s < 32; ++s) {
                        if (taken & (1u << s)) continue;
                        const float v = r[s];
                        const int j = s * 64 + lane;
                        if (v > v1)      { v2 = v1; i2 = i1; v1 = v; i1 = j; }
                        else if (v > v2) { v2 = v; i2 = j; }
                    }
                    incache = (rem >= 2) ? 2 : rem;
                    rem -= incache;
                }
            }
        }

        float e = 0.f;
        if (lane < nsel) e = __expf(selv_r - m);
        float Z = e;
#pragma unroll
        for (int mask = 1; mask < 32; mask <<= 1) Z += __shfl_xor(Z, mask, 64);
        if (lane < nsel) {
            const float w = e / Z;
            selw[wave][lane] = w;
            selidx[wave][lane] = seli_r;
            atomicAdd(&am[seli_r], w);
        }

        float acc = 0.f;
        for (int i = 0; i < nsel; ++i) {
            const int idx = selidx[wave][i];
            const float ww = selw[wave][i];
            acc += ww * Vb[(size_t)idx * DHEAD + lane];
        }
        ctx[(((size_t)(b * NTOK + q)) * HEADS + h) * DHEAD + lane] = acc;
    }

    __syncthreads();
    const float invH = 1.0f / (float)HEADS;
    float* arow = attn_out + ((size_t)(b * NTOK + q)) * NTOK;
    for (int j = tid; j < NTOK; j += 256) arow[j] = am[j] * invH;
}

// ---------------------------------------------------------------------------
// Fallback fused attention — only if ws can't fit a QC=64 score chunk.
// ---------------------------------------------------------------------------
__global__ __launch_bounds__(256) void attn_kernel(const float* __restrict__ Q,
                                                   const float* __restrict__ K,
                                                   const float* __restrict__ V,
                                                   float* __restrict__ ctx,
                                                   float* __restrict__ attn_out)
{
    const int blk = blockIdx.x;
    const int b = blk >> 11;
    const int q = blk & (NTOK - 1);
    const int tid = threadIdx.x;
    const int wave = tid >> 6;
    const int lane = tid & 63;

    __shared__ float sc[4][NTOK];
    __shared__ float am[NTOK];
    __shared__ float selv[4][KSEL];
    __shared__ int   seli[4][KSEL];
    __shared__ float selw[4][KSEL];

    for (int j = tid; j < NTOK; j += 256) am[j] = 0.f;
    __syncthreads();

    const int L = q + 1;
    const int nsel = (L < KSEL) ? L : KSEL;

    for (int hg = 0; hg < 4; ++hg) {
        const int h = hg * 4 + wave;
        const size_t bh = (size_t)(b * HEADS + h);
        const float* Qrow = Q + (bh * NTOK + q) * DHEAD;
        const float* Kb = K + bh * NTOK * DHEAD;
        const float* Vb = V + bh * NTOK * DHEAD;

        float4 qr[16];
#pragma unroll
        for (int d4 = 0; d4 < 16; ++d4) qr[d4] = ((const float4*)Qrow)[d4];

        float lm = -INFINITY; int li = -1;
        for (int j = lane; j < L; j += 64) {
            const float4* kr = (const float4*)(Kb + (size_t)j * DHEAD);
            float a0 = 0.f, a1 = 0.f, a2 = 0.f, a3 = 0.f;
#pragma unroll
            for (int d4 = 0; d4 < 16; ++d4) {
                const float4 kk = kr[d4];
                a0 += qr[d4].x * kk.x;
                a1 += qr[d4].y * kk.y;
                a2 += qr[d4].z * kk.z;
                a3 += qr[d4].w * kk.w;
            }
            const float s = (a0 + a1 + a2 + a3) * 0.125f;
            sc[wave][j] = s;
            if (s > lm) { lm = s; li = j; }
        }

        for (int it = 0; it < nsel; ++it) {
            float bmv = lm; int bi = li;
#pragma unroll
            for (int mask = 1; mask < 64; mask <<= 1) {
                const float ov = __shfl_xor(bmv, mask, 64);
                const int   oi = __shfl_xor(bi, mask, 64);
                if (ov > bmv || (ov == bmv && (unsigned)oi < (unsigned)bi)) {
                    bmv = ov; bi = oi;
                }
            }
            if (lane == (bi & 63)) {
                sc[wave][bi] = -INFINITY;
                lm = -INFINITY; li = -1;
                for (int j = lane; j < L; j += 64) {
                    const float s = sc[wave][j];
                    if (s > lm) { lm = s; li = j; }
                }
            }
            if (lane == 0) { selv[wave][it] = bmv; seli[wave][it] = bi; }
        }

        const float m = selv[wave][0];
        float e = 0.f;
        if (lane < nsel) e = expf(selv[wave][lane] - m);
        float Z = e;
#pragma unroll
        for (int mask = 1; mask < 32; mask <<= 1) Z += __shfl_xor(Z, mask, 64);
        if (lane < nsel) {
            const float w = e / Z;
            selw[wave][lane] = w;
            atomicAdd(&am[seli[wave][lane]], w);
        }

        float acc = 0.f;
        for (int i = 0; i < nsel; ++i) {
            const int idx = seli[wave][i];
            const float w = selw[wave][i];
            acc += w * Vb[(size_t)idx * DHEAD + lane];
        }
        ctx[(((size_t)(b * NTOK + q)) * HEADS + h) * DHEAD + lane] = acc;
    }

    __syncthreads();
    const float invH = 1.0f / (float)HEADS;
    float* arow = attn_out + ((size_t)(b * NTOK + q)) * NTOK;
    for (int j = tid; j < NTOK; j += 256) arow[j] = am[j] * invH;
}

// ---------------------------------------------------------------------------
extern "C" void kernel_launch(void* const* d_in, const int* in_sizes, int n_in,
                              void* d_out, int out_size, void* d_ws, size_t ws_size,
                              hipStream_t stream) {
    const float* x  = (const float*)d_in[0];
    const float* Wq = (const float*)d_in[1];
    const float* bq = (const float*)d_in[2];
    const float* Wk = (const float*)d_in[3];
    const float* bk = (const float*)d_in[4];
    const float* Wv = (const float*)d_in[5];
    const float* bv = (const float*)d_in[6];
    const float* Wo = (const float*)d_in[7];
    const float* bo = (const float*)d_in[8];

    const size_t MB = 1ull << 20;
    char* wsb = (char*)d_ws;
    // fp32 buffers (16 MB each)
    float* Qws = (float*)(wsb + 0 * MB);
    float* Kws = (float*)(wsb + 16 * MB);
    float* Vws = (float*)(wsb + 32 * MB);
    float* ctx = (float*)(wsb + 48 * MB);
    // bf16 split buffers
    ushort_t* xhi = (ushort_t*)(wsb + 64 * MB);  // 8 MB
    ushort_t* xlo = (ushort_t*)(wsb + 72 * MB);  // 8 MB
    ushort_t* wqh = (ushort_t*)(wsb + 80 * MB);  // 2 MB each
    ushort_t* wql = (ushort_t*)(wsb + 82 * MB);
    ushort_t* wkh = (ushort_t*)(wsb + 84 * MB);
    ushort_t* wkl = (ushort_t*)(wsb + 86 * MB);
    ushort_t* wvh = (ushort_t*)(wsb + 88 * MB);
    ushort_t* wvl = (ushort_t*)(wsb + 90 * MB);
    ushort_t* woh = (ushort_t*)(wsb + 92 * MB);
    ushort_t* wol = (ushort_t*)(wsb + 94 * MB);
    // ctx split reuses the x region (x dead after QKV projections)
    ushort_t* cxh = xhi;
    ushort_t* cxl = xlo;
    float*    Sws = (float*)(wsb + 96 * MB);     // score chunk buffer

    float* y    = (float*)d_out;
    float* attn = y + (size_t)BATCH * NTOK * DMODEL;

    const int NX = MROWS * DMODEL;   // 4 M
    const int NW = DMODEL * DMODEL;  // 1 M

    // ---- bf16 split conversions
    conv_split<<<NX / (256 * 4), 256, 0, stream>>>(x, xhi, xlo, NX);
    conv_split<<<NW / (256 * 4), 256, 0, stream>>>(Wq, wqh, wql, NW);
    conv_split<<<NW / (256 * 4), 256, 0, stream>>>(Wk, wkh, wkl, NW);
    conv_split<<<NW / (256 * 4), 256, 0, stream>>>(Wv, wvh, wvl, NW);
    conv_split<<<NW / (256 * 4), 256, 0, stream>>>(Wo, woh, wol, NW);

    // ---- Q/K/V projections (split-bf16 MFMA)
    dim3 ggrid(MROWS / 128, DMODEL / 64);
    gemm_split_mfma<<<ggrid, 256, 0, stream>>>(xhi, xlo, wqh, wql, bq, Qws, 1);
    gemm_split_mfma<<<ggrid, 256, 0, stream>>>(xhi, xlo, wkh, wkl, bk, Kws, 1);
    gemm_split_mfma<<<ggrid, 256, 0, stream>>>(xhi, xlo, wvh, wvl, bv, Vws, 1);

    // ---- attention: largest power-of-two q-chunk fitting after 96 MB base
    const size_t base_bytes = 96 * MB;
    const size_t avail = (ws_size > base_bytes) ? ws_size - base_bytes : 0;
    int QC = 0;
    for (int cand = NTOK; cand >= 64; cand >>= 1) {
        const size_t need = (size_t)BATCH * HEADS * cand * NTOK * sizeof(float);
        if (need <= avail) { QC = cand; break; }
    }

    if (QC > 0) {
        for (int q0 = 0; q0 < NTOK; q0 += QC) {
            dim3 sgrid((q0 + QC) / 64, QC / 64, BATCH * HEADS);
            score_chunk<<<sgrid, 256, 0, stream>>>(Qws, Kws, Sws, q0, QC);
            dim3 selgrid(QC, BATCH);
            select_chunk<<<selgrid, 256, 0, stream>>>(Sws, Vws, ctx, attn, q0, QC);
        }
    } else {
        attn_kernel<<<BATCH * NTOK, 256, 0, stream>>>(Qws, Kws, Vws, ctx, attn);
    }

    // ---- output projection (split-bf16 MFMA)
    conv_split<<<NX / (256 * 4), 256, 0, stream>>>(ctx, cxh, cxl, NX);
    gemm_split_mfma<<<ggrid, 256, 0, stream>>>(cxh, cxl, woh, wol, bo, y, 0);
}

// Round 7
// 1021.056 us; speedup vs baseline: 3.2205x; 1.0614x over previous
//
#include <hip/hip_runtime.h>
#include <hip/hip_bf16.h>
#include <math.h>

// Problem constants
#define BATCH   2
#define NTOK    2048
#define DMODEL  1024
#define HEADS   16
#define DHEAD   64
#define KSEL    32
#define MROWS   (BATCH * NTOK)   // 4096

typedef short     bf16x8 __attribute__((ext_vector_type(8)));
typedef float     f32x4  __attribute__((ext_vector_type(4)));
typedef unsigned short ushort_t;
typedef unsigned long long u64;

#define GLOAD_LDS16(g, l) \
    __builtin_amdgcn_global_load_lds((const __attribute__((address_space(1))) void*)(g), \
                                     (__attribute__((address_space(3))) void*)(l), 16, 0, 0)

// ---------------------------------------------------------------------------
// f32 -> (hi, lo) bf16 split: hi = bf16(x), lo = bf16(x - hi)
// ---------------------------------------------------------------------------
__device__ __forceinline__ ushort_t f2bf(float f) {
    unsigned u = __float_as_uint(f);
    unsigned r = (u + 0x7FFFu + ((u >> 16) & 1u)) >> 16;
    return (ushort_t)r;
}
__device__ __forceinline__ float bf2f(ushort_t h) {
    return __uint_as_float(((unsigned)h) << 16);
}

__global__ __launch_bounds__(256) void conv_split(const float* __restrict__ in,
                                                  ushort_t* __restrict__ hi,
                                                  ushort_t* __restrict__ lo, int n)
{
    const int i = (blockIdx.x * 256 + threadIdx.x) * 4;
    if (i + 3 < n) {
        const float4 v = *(const float4*)(in + i);
        ushort4 ph, pl;
        ph.x = f2bf(v.x); pl.x = f2bf(v.x - bf2f(ph.x));
        ph.y = f2bf(v.y); pl.y = f2bf(v.y - bf2f(ph.y));
        ph.z = f2bf(v.z); pl.z = f2bf(v.z - bf2f(ph.z));
        ph.w = f2bf(v.w); pl.w = f2bf(v.w - bf2f(ph.w));
        *(ushort4*)(hi + i) = ph;
        *(ushort4*)(lo + i) = pl;
    }
}

__global__ __launch_bounds__(256) void zero_fill(float* __restrict__ p, int n4)
{
    const int i = blockIdx.x * 256 + threadIdx.x;
    if (i < n4) ((float4*)p)[i] = (float4){0.f, 0.f, 0.f, 0.f};
}

// ---------------------------------------------------------------------------
// Split-bf16 MFMA GEMM: C = A*B^T + bias (fp32-class accuracy via 3 MFMAs)
// ---------------------------------------------------------------------------
__global__ __launch_bounds__(256) void gemm_split_mfma(const ushort_t* __restrict__ Ahi,
                                                       const ushort_t* __restrict__ Alo,
                                                       const ushort_t* __restrict__ Bhi,
                                                       const ushort_t* __restrict__ Blo,
                                                       const float* __restrict__ bias,
                                                       float* __restrict__ out,
                                                       int scatter)
{
    __shared__ ushort_t AbufH[128 * 32];
    __shared__ ushort_t AbufL[128 * 32];
    __shared__ ushort_t BbufH[64 * 32];
    __shared__ ushort_t BbufL[64 * 32];

    const int tid  = threadIdx.x;
    const int wave = tid >> 6;
    const int lane = tid & 63;
    const int m0 = blockIdx.x * 128;
    const int n0 = blockIdx.y * 64;

    f32x4 acc[2][4];
#pragma unroll
    for (int i = 0; i < 2; ++i)
#pragma unroll
        for (int j = 0; j < 4; ++j) acc[i][j] = (f32x4){0.f, 0.f, 0.f, 0.f};

    const int ar0 = tid >> 2;
    const int ar1 = 64 + (tid >> 2);
    const int ak  = (tid & 3) << 3;
    const int br  = tid >> 2;

    const int fr = lane & 15;
    const int fk = (lane >> 4) << 3;

    for (int k0 = 0; k0 < DMODEL; k0 += 32) {
        __syncthreads();
        const size_t aoff0 = (size_t)(m0 + ar0) * DMODEL + k0 + ak;
        const size_t aoff1 = (size_t)(m0 + ar1) * DMODEL + k0 + ak;
        const size_t boff  = (size_t)(n0 + br) * DMODEL + k0 + ak;
        GLOAD_LDS16(Ahi + aoff0, AbufH + (size_t)tid * 8);
        GLOAD_LDS16(Ahi + aoff1, AbufH + (size_t)(256 + tid) * 8);
        GLOAD_LDS16(Alo + aoff0, AbufL + (size_t)tid * 8);
        GLOAD_LDS16(Alo + aoff1, AbufL + (size_t)(256 + tid) * 8);
        GLOAD_LDS16(Bhi + boff, BbufH + (size_t)tid * 8);
        GLOAD_LDS16(Blo + boff, BbufL + (size_t)tid * 8);
        __syncthreads();

        bf16x8 afh[2], afl[2], bfh[4], bfl[4];
#pragma unroll
        for (int mi = 0; mi < 2; ++mi) {
            const int ro = (wave * 32 + mi * 16 + fr) * 32 + fk;
            afh[mi] = *(const bf16x8*)(AbufH + ro);
            afl[mi] = *(const bf16x8*)(AbufL + ro);
        }
#pragma unroll
        for (int ni = 0; ni < 4; ++ni) {
            const int ro = (ni * 16 + fr) * 32 + fk;
            bfh[ni] = *(const bf16x8*)(BbufH + ro);
            bfl[ni] = *(const bf16x8*)(BbufL + ro);
        }

#pragma unroll
        for (int mi = 0; mi < 2; ++mi)
#pragma unroll
            for (int ni = 0; ni < 4; ++ni) {
                acc[mi][ni] = __builtin_amdgcn_mfma_f32_16x16x32_bf16(afh[mi], bfl[ni], acc[mi][ni], 0, 0, 0);
                acc[mi][ni] = __builtin_amdgcn_mfma_f32_16x16x32_bf16(afl[mi], bfh[ni], acc[mi][ni], 0, 0, 0);
                acc[mi][ni] = __builtin_amdgcn_mfma_f32_16x16x32_bf16(afh[mi], bfh[ni], acc[mi][ni], 0, 0, 0);
            }
    }

#pragma unroll
    for (int ni = 0; ni < 4; ++ni) {
        const int o = n0 + ni * 16 + (lane & 15);
        const float bv = bias[o];
#pragma unroll
        for (int mi = 0; mi < 2; ++mi) {
#pragma unroll
            for (int reg = 0; reg < 4; ++reg) {
                const int m = m0 + wave * 32 + mi * 16 + ((lane >> 4) << 2) + reg;
                const float v = acc[mi][ni][reg] + bv;
                if (scatter) {
                    const int bb = m >> 11;
                    const int n  = m & 2047;
                    const int h  = o >> 6;
                    const int d  = o & 63;
                    out[(((size_t)(bb * HEADS + h)) * NTOK + n) * DHEAD + d] = v;
                } else {
                    out[(size_t)m * DMODEL + o] = v;
                }
            }
        }
    }
}

// ---------------------------------------------------------------------------
// score_chunk: S[bh, q_local, k] = (Q[bh, q0+q_local, :] . K[bh, k, :]) / 8
// ---------------------------------------------------------------------------
__global__ __launch_bounds__(256) void score_chunk(const float* __restrict__ Q,
                                                   const float* __restrict__ K,
                                                   float* __restrict__ S,
                                                   int q0, int QC)
{
    const int kt = blockIdx.x;
    const int qt = blockIdx.y;
    const int qt_g = (q0 >> 6) + qt;
    if (kt > qt_g) return;
    const int bh = blockIdx.z;

    __shared__ float As[16][65];
    __shared__ float Bs[16][65];

    const int tid = threadIdx.x;
    const int tx = tid & 15;
    const int ty = tid >> 4;
    const int lr = tid >> 2;
    const int lc = (tid & 3) << 2;

    const float* Qb = Q + ((size_t)bh * NTOK + q0 + qt * 64) * DHEAD;
    const float* Kb = K + ((size_t)bh * NTOK + kt * 64) * DHEAD;

    float acc[4][4];
#pragma unroll
    for (int i = 0; i < 4; ++i)
#pragma unroll
        for (int j = 0; j < 4; ++j) acc[i][j] = 0.f;

#pragma unroll
    for (int k0 = 0; k0 < DHEAD; k0 += 16) {
        float4 av = *(const float4*)(Qb + (size_t)lr * DHEAD + k0 + lc);
        float4 bv = *(const float4*)(Kb + (size_t)lr * DHEAD + k0 + lc);
        As[lc + 0][lr] = av.x; As[lc + 1][lr] = av.y;
        As[lc + 2][lr] = av.z; As[lc + 3][lr] = av.w;
        Bs[lc + 0][lr] = bv.x; Bs[lc + 1][lr] = bv.y;
        Bs[lc + 2][lr] = bv.z; Bs[lc + 3][lr] = bv.w;
        __syncthreads();
#pragma unroll
        for (int kk = 0; kk < 16; ++kk) {
            float a0 = As[kk][ty * 4 + 0];
            float a1 = As[kk][ty * 4 + 1];
            float a2 = As[kk][ty * 4 + 2];
            float a3 = As[kk][ty * 4 + 3];
            float b0 = Bs[kk][tx * 4 + 0];
            float b1 = Bs[kk][tx * 4 + 1];
            float b2 = Bs[kk][tx * 4 + 2];
            float b3 = Bs[kk][tx * 4 + 3];
            acc[0][0] += a0 * b0; acc[0][1] += a0 * b1; acc[0][2] += a0 * b2; acc[0][3] += a0 * b3;
            acc[1][0] += a1 * b0; acc[1][1] += a1 * b1; acc[1][2] += a1 * b2; acc[1][3] += a1 * b3;
            acc[2][0] += a2 * b0; acc[2][1] += a2 * b1; acc[2][2] += a2 * b2; acc[2][3] += a2 * b3;
            acc[3][0] += a3 * b0; acc[3][1] += a3 * b1; acc[3][2] += a3 * b2; acc[3][3] += a3 * b3;
        }
        __syncthreads();
    }

#pragma unroll
    for (int i = 0; i < 4; ++i) {
        const int ql = qt * 64 + ty * 4 + i;
        float* Srow = S + ((size_t)bh * QC + ql) * NTOK;
#pragma unroll
        for (int j = 0; j < 4; ++j) {
            const int k = kt * 64 + tx * 4 + j;
            Srow[k] = acc[i][j] * 0.125f;
        }
    }
}

// ---------------------------------------------------------------------------
// select_v3: one wave per (q,h). Packed u64 keys (mono(value)+1)<<32 | ~j:
// single 6-step butterfly per extraction (value max, min-index tiebreak).
// L-tiered SLOTS. No LDS, no barriers. attn-mean via global atomics into
// pre-zeroed attn. Selection set & softmax inputs bit-identical to v2.
// ---------------------------------------------------------------------------
__device__ __forceinline__ unsigned mono_key(float f) {
    const unsigned u = __float_as_uint(f);
    return (u ^ (unsigned)(((int)u >> 31) | 0x80000000)) + 1u;
}
__device__ __forceinline__ float unmono(unsigned m) {
    const unsigned u = m - 1u;
    return __uint_as_float(u ^ (unsigned)(((int)(~u) >> 31) | 0x80000000));
}

template<int SLOTS>
__device__ __forceinline__ void select_task(const float* __restrict__ Srow,
                                            const float* __restrict__ Vb,
                                            float* __restrict__ ctxRow,
                                            float* __restrict__ attnRow,
                                            int L, int nsel)
{
    const int lane = threadIdx.x & 63;

    // ---- load scores, map to monotone keys (0 = empty)
    unsigned km[SLOTS];
    int valid = 0;
#pragma unroll
    for (int s = 0; s < SLOTS; ++s) {
        const int j = s * 64 + lane;
        unsigned m = 0u;
        if (j < L) { m = mono_key(Srow[j]); ++valid; }
        km[s] = m;
    }

    // ---- per-lane top-2 cache of packed u64 keys
    u64 k1 = 0, k2 = 0;
#pragma unroll
    for (int s = 0; s < SLOTS; ++s) {
        const u64 k = (km[s] == 0u) ? 0ull
                      : (((u64)km[s] << 32) | (unsigned)~(s * 64 + lane));
        if (k > k1) { k2 = k1; k1 = k; }
        else if (k > k2) { k2 = k; }
    }
    int incache = (valid >= 2) ? 2 : valid;
    int rem = valid - incache;
    unsigned taken = 0u;

    u64 myk = 0;          // lane it holds extraction it
    unsigned mono0 = 0;   // mono of global max (uniform)

    for (int it = 0; it < nsel; ++it) {
        u64 b = k1;
#pragma unroll
        for (int mask = 1; mask < 64; mask <<= 1) {
            const u64 o = __shfl_xor(b, mask, 64);
            b = (o > b) ? o : b;
        }
        const unsigned gidx = ~(unsigned)b;   // global index of winner
        if (it == 0) mono0 = (unsigned)(b >> 32);
        if (lane == it) myk = b;

        if (lane == (int)(gidx & 63u)) {
            taken |= 1u << (gidx >> 6);
            k1 = k2; k2 = 0; --incache;
            if (incache == 0 && rem > 0) {
                k1 = 0;
#pragma unroll
                for (int s = 0; s < SLOTS; ++s) {
                    if (taken & (1u << s)) continue;
                    const u64 k = (km[s] == 0u) ? 0ull
                                  : (((u64)km[s] << 32) | (unsigned)~(s * 64 + lane));
                    if (k > k1) { k2 = k1; k1 = k; }
                    else if (k > k2) { k2 = k; }
                }
                incache = (rem >= 2) ? 2 : rem;
                rem -= incache;
            }
        }
    }

    // ---- softmax over selected (lane i holds extraction i; i < nsel <= 32)
    const float vmax = unmono(mono0);
    float e = 0.f;
    if (lane < nsel) e = __expf(unmono((unsigned)(myk >> 32)) - vmax);
    float Z = e;
#pragma unroll
    for (int mask = 1; mask < 32; mask <<= 1) Z += __shfl_xor(Z, mask, 64);
    const float w = (lane < nsel) ? e / Z : 0.f;

    // attn-mean contribution (attn pre-zeroed)
    if (lane < nsel) {
        const int idx = (int)(~(unsigned)myk);
        atomicAdd(&attnRow[idx], w * (1.0f / (float)HEADS));
    }

    // ---- ctx[d=lane] = sum_i w_i * V[idx_i, lane]  via readlane broadcast
    float acc = 0.f;
    for (int i = 0; i < nsel; ++i) {
        const u64 ki = __shfl(myk, i, 64);
        const float wi = __shfl(w, i, 64);
        const int idx = (int)(~(unsigned)ki);
        acc += wi * Vb[(size_t)idx * DHEAD + lane];
    }
    ctxRow[lane] = acc;
}

__global__ __launch_bounds__(256) void select_v3(const float* __restrict__ S,
                                                 const float* __restrict__ V,
                                                 float* __restrict__ ctx,
                                                 float* __restrict__ attn,
                                                 int q0, int QC)
{
    const int wave = threadIdx.x >> 6;
    const int ql = blockIdx.x;
    const int b  = blockIdx.y >> 2;
    const int hg = blockIdx.y & 3;
    const int h  = hg * 4 + wave;
    const int q  = q0 + ql;
    const int L = q + 1;
    const int nsel = (L < KSEL) ? L : KSEL;

    const size_t bh = (size_t)(b * HEADS + h);
    const float* Srow = S + (bh * QC + ql) * NTOK;
    const float* Vb   = V + bh * NTOK * DHEAD;
    float* ctxRow  = ctx + (((size_t)(b * NTOK + q)) * HEADS + h) * DHEAD;
    float* attnRow = attn + ((size_t)(b * NTOK + q)) * NTOK;

    if (q < 512)       select_task<8 >(Srow, Vb, ctxRow, attnRow, L, nsel);
    else if (q < 1024) select_task<16>(Srow, Vb, ctxRow, attnRow, L, nsel);
    else               select_task<32>(Srow, Vb, ctxRow, attnRow, L, nsel);
}

// ---------------------------------------------------------------------------
// Fallback fused attention — only if ws can't fit a QC=64 score chunk.
// ---------------------------------------------------------------------------
__global__ __launch_bounds__(256) void attn_kernel(const float* __restrict__ Q,
                                                   const float* __restrict__ K,
                                                   const float* __restrict__ V,
                                                   float* __restrict__ ctx,
                                                   float* __restrict__ attn_out)
{
    const int blk = blockIdx.x;
    const int b = blk >> 11;
    const int q = blk & (NTOK - 1);
    const int tid = threadIdx.x;
    const int wave = tid >> 6;
    const int lane = tid & 63;

    __shared__ float sc[4][NTOK];
    __shared__ float am[NTOK];
    __shared__ float selv[4][KSEL];
    __shared__ int   seli[4][KSEL];
    __shared__ float selw[4][KSEL];

    for (int j = tid; j < NTOK; j += 256) am[j] = 0.f;
    __syncthreads();

    const int L = q + 1;
    const int nsel = (L < KSEL) ? L : KSEL;

    for (int hg = 0; hg < 4; ++hg) {
        const int h = hg * 4 + wave;
        const size_t bh = (size_t)(b * HEADS + h);
        const float* Qrow = Q + (bh * NTOK + q) * DHEAD;
        const float* Kb = K + bh * NTOK * DHEAD;
        const float* Vb = V + bh * NTOK * DHEAD;

        float4 qr[16];
#pragma unroll
        for (int d4 = 0; d4 < 16; ++d4) qr[d4] = ((const float4*)Qrow)[d4];

        float lm = -INFINITY; int li = -1;
        for (int j = lane; j < L; j += 64) {
            const float4* kr = (const float4*)(Kb + (size_t)j * DHEAD);
            float a0 = 0.f, a1 = 0.f, a2 = 0.f, a3 = 0.f;
#pragma unroll
            for (int d4 = 0; d4 < 16; ++d4) {
                const float4 kk = kr[d4];
                a0 += qr[d4].x * kk.x;
                a1 += qr[d4].y * kk.y;
                a2 += qr[d4].z * kk.z;
                a3 += qr[d4].w * kk.w;
            }
            const float s = (a0 + a1 + a2 + a3) * 0.125f;
            sc[wave][j] = s;
            if (s > lm) { lm = s; li = j; }
        }

        for (int it = 0; it < nsel; ++it) {
            float bmv = lm; int bi = li;
#pragma unroll
            for (int mask = 1; mask < 64; mask <<= 1) {
                const float ov = __shfl_xor(bmv, mask, 64);
                const int   oi = __shfl_xor(bi, mask, 64);
                if (ov > bmv || (ov == bmv && (unsigned)oi < (unsigned)bi)) {
                    bmv = ov; bi = oi;
                }
            }
            if (lane == (bi & 63)) {
                sc[wave][bi] = -INFINITY;
                lm = -INFINITY; li = -1;
                for (int j = lane; j < L; j += 64) {
                    const float s = sc[wave][j];
                    if (s > lm) { lm = s; li = j; }
                }
            }
            if (lane == 0) { selv[wave][it] = bmv; seli[wave][it] = bi; }
        }

        const float m = selv[wave][0];
        float e = 0.f;
        if (lane < nsel) e = expf(selv[wave][lane] - m);
        float Z = e;
#pragma unroll
        for (int mask = 1; mask < 32; mask <<= 1) Z += __shfl_xor(Z, mask, 64);
        if (lane < nsel) {
            const float w = e / Z;
            selw[wave][lane] = w;
            atomicAdd(&am[seli[wave][lane]], w);
        }

        float acc = 0.f;
        for (int i = 0; i < nsel; ++i) {
            const int idx = seli[wave][i];
            const float w = selw[wave][i];
            acc += w * Vb[(size_t)idx * DHEAD + lane];
        }
        ctx[(((size_t)(b * NTOK + q)) * HEADS + h) * DHEAD + lane] = acc;
    }

    __syncthreads();
    const float invH = 1.0f / (float)HEADS;
    float* arow = attn_out + ((size_t)(b * NTOK + q)) * NTOK;
    for (int j = tid; j < NTOK; j += 256) arow[j] = am[j] * invH;
}

// ---------------------------------------------------------------------------
extern "C" void kernel_launch(void* const* d_in, const int* in_sizes, int n_in,
                              void* d_out, int out_size, void* d_ws, size_t ws_size,
                              hipStream_t stream) {
    const float* x  = (const float*)d_in[0];
    const float* Wq = (const float*)d_in[1];
    const float* bq = (const float*)d_in[2];
    const float* Wk = (const float*)d_in[3];
    const float* bk = (const float*)d_in[4];
    const float* Wv = (const float*)d_in[5];
    const float* bv = (const float*)d_in[6];
    const float* Wo = (const float*)d_in[7];
    const float* bo = (const float*)d_in[8];

    const size_t MB = 1ull << 20;
    char* wsb = (char*)d_ws;
    float* Qws = (float*)(wsb + 0 * MB);
    float* Kws = (float*)(wsb + 16 * MB);
    float* Vws = (float*)(wsb + 32 * MB);
    float* ctx = (float*)(wsb + 48 * MB);
    ushort_t* xhi = (ushort_t*)(wsb + 64 * MB);
    ushort_t* xlo = (ushort_t*)(wsb + 72 * MB);
    ushort_t* wqh = (ushort_t*)(wsb + 80 * MB);
    ushort_t* wql = (ushort_t*)(wsb + 82 * MB);
    ushort_t* wkh = (ushort_t*)(wsb + 84 * MB);
    ushort_t* wkl = (ushort_t*)(wsb + 86 * MB);
    ushort_t* wvh = (ushort_t*)(wsb + 88 * MB);
    ushort_t* wvl = (ushort_t*)(wsb + 90 * MB);
    ushort_t* woh = (ushort_t*)(wsb + 92 * MB);
    ushort_t* wol = (ushort_t*)(wsb + 94 * MB);
    ushort_t* cxh = xhi;   // reuse (x dead after QKV)
    ushort_t* cxl = xlo;
    float*    Sws = (float*)(wsb + 96 * MB);

    float* y    = (float*)d_out;
    float* attn = y + (size_t)BATCH * NTOK * DMODEL;

    const int NX = MROWS * DMODEL;
    const int NW = DMODEL * DMODEL;

    // ---- bf16 split conversions
    conv_split<<<NX / (256 * 4), 256, 0, stream>>>(x, xhi, xlo, NX);
    conv_split<<<NW / (256 * 4), 256, 0, stream>>>(Wq, wqh, wql, NW);
    conv_split<<<NW / (256 * 4), 256, 0, stream>>>(Wk, wkh, wkl, NW);
    conv_split<<<NW / (256 * 4), 256, 0, stream>>>(Wv, wvh, wvl, NW);
    conv_split<<<NW / (256 * 4), 256, 0, stream>>>(Wo, woh, wol, NW);

    // ---- Q/K/V projections (split-bf16 MFMA)
    dim3 ggrid(MROWS / 128, DMODEL / 64);
    gemm_split_mfma<<<ggrid, 256, 0, stream>>>(xhi, xlo, wqh, wql, bq, Qws, 1);
    gemm_split_mfma<<<ggrid, 256, 0, stream>>>(xhi, xlo, wkh, wkl, bk, Kws, 1);
    gemm_split_mfma<<<ggrid, 256, 0, stream>>>(xhi, xlo, wvh, wvl, bv, Vws, 1);

    // ---- attention
    const size_t base_bytes = 96 * MB;
    const size_t avail = (ws_size > base_bytes) ? ws_size - base_bytes : 0;
    int QC = 0;
    for (int cand = NTOK; cand >= 64; cand >>= 1) {
        const size_t need = (size_t)BATCH * HEADS * cand * NTOK * sizeof(float);
        if (need <= avail) { QC = cand; break; }
    }

    if (QC > 0) {
        const int nattn4 = BATCH * NTOK * NTOK / 4;
        zero_fill<<<(nattn4 + 255) / 256, 256, 0, stream>>>(attn, nattn4);
        for (int q0 = 0; q0 < NTOK; q0 += QC) {
            dim3 sgrid((q0 + QC) / 64, QC / 64, BATCH * HEADS);
            score_chunk<<<sgrid, 256, 0, stream>>>(Qws, Kws, Sws, q0, QC);
            dim3 selgrid(QC, BATCH * 4);
            select_v3<<<selgrid, 256, 0, stream>>>(Sws, Vws, ctx, attn, q0, QC);
        }
    } else {
        attn_kernel<<<BATCH * NTOK, 256, 0, stream>>>(Qws, Kws, Vws, ctx, attn);
    }

    // ---- output projection (split-bf16 MFMA)
    conv_split<<<NX / (256 * 4), 256, 0, stream>>>(ctx, cxh, cxl, NX);
    gemm_split_mfma<<<ggrid, 256, 0, stream>>>(cxh, cxl, woh, wol, bo, y, 0);
}

// Round 8
// 766.827 us; speedup vs baseline: 4.2882x; 1.3315x over previous
//
#include <hip/hip_runtime.h>
#include <hip/hip_bf16.h>
#include <math.h>

// Problem constants
#define BATCH   2
#define NTOK    2048
#define DMODEL  1024
#define HEADS   16
#define DHEAD   64
#define KSEL    32
#define MROWS   (BATCH * NTOK)   // 4096

typedef short     bf16x8 __attribute__((ext_vector_type(8)));
typedef float     f32x4  __attribute__((ext_vector_type(4)));
typedef unsigned short ushort_t;
typedef unsigned long long u64;

#define GLOAD_LDS16(g, l) \
    __builtin_amdgcn_global_load_lds((const __attribute__((address_space(1))) void*)(g), \
                                     (__attribute__((address_space(3))) void*)(l), 16, 0, 0)

// ---------------------------------------------------------------------------
// f32 -> (hi, lo) bf16 split: hi = bf16(x), lo = bf16(x - hi)
// ---------------------------------------------------------------------------
__device__ __forceinline__ ushort_t f2bf(float f) {
    unsigned u = __float_as_uint(f);
    unsigned r = (u + 0x7FFFu + ((u >> 16) & 1u)) >> 16;
    return (ushort_t)r;
}
__device__ __forceinline__ float bf2f(ushort_t h) {
    return __uint_as_float(((unsigned)h) << 16);
}

__global__ __launch_bounds__(256) void conv_split(const float* __restrict__ in,
                                                  ushort_t* __restrict__ hi,
                                                  ushort_t* __restrict__ lo, int n)
{
    const int i = (blockIdx.x * 256 + threadIdx.x) * 4;
    if (i + 3 < n) {
        const float4 v = *(const float4*)(in + i);
        ushort4 ph, pl;
        ph.x = f2bf(v.x); pl.x = f2bf(v.x - bf2f(ph.x));
        ph.y = f2bf(v.y); pl.y = f2bf(v.y - bf2f(ph.y));
        ph.z = f2bf(v.z); pl.z = f2bf(v.z - bf2f(ph.z));
        ph.w = f2bf(v.w); pl.w = f2bf(v.w - bf2f(ph.w));
        *(ushort4*)(hi + i) = ph;
        *(ushort4*)(lo + i) = pl;
    }
}

__global__ __launch_bounds__(256) void zero_fill(float* __restrict__ p, int n4)
{
    const int i = blockIdx.x * 256 + threadIdx.x;
    if (i < n4) ((float4*)p)[i] = (float4){0.f, 0.f, 0.f, 0.f};
}

// ---------------------------------------------------------------------------
// Split-bf16 MFMA GEMM: C = A*B^T + bias (fp32-class accuracy via 3 MFMAs)
// ---------------------------------------------------------------------------
__global__ __launch_bounds__(256) void gemm_split_mfma(const ushort_t* __restrict__ Ahi,
                                                       const ushort_t* __restrict__ Alo,
                                                       const ushort_t* __restrict__ Bhi,
                                                       const ushort_t* __restrict__ Blo,
                                                       const float* __restrict__ bias,
                                                       float* __restrict__ out,
                                                       int scatter)
{
    __shared__ ushort_t AbufH[128 * 32];
    __shared__ ushort_t AbufL[128 * 32];
    __shared__ ushort_t BbufH[64 * 32];
    __shared__ ushort_t BbufL[64 * 32];

    const int tid  = threadIdx.x;
    const int wave = tid >> 6;
    const int lane = tid & 63;
    const int m0 = blockIdx.x * 128;
    const int n0 = blockIdx.y * 64;

    f32x4 acc[2][4];
#pragma unroll
    for (int i = 0; i < 2; ++i)
#pragma unroll
        for (int j = 0; j < 4; ++j) acc[i][j] = (f32x4){0.f, 0.f, 0.f, 0.f};

    const int ar0 = tid >> 2;
    const int ar1 = 64 + (tid >> 2);
    const int ak  = (tid & 3) << 3;
    const int br  = tid >> 2;

    const int fr = lane & 15;
    const int fk = (lane >> 4) << 3;

    for (int k0 = 0; k0 < DMODEL; k0 += 32) {
        __syncthreads();
        const size_t aoff0 = (size_t)(m0 + ar0) * DMODEL + k0 + ak;
        const size_t aoff1 = (size_t)(m0 + ar1) * DMODEL + k0 + ak;
        const size_t boff  = (size_t)(n0 + br) * DMODEL + k0 + ak;
        GLOAD_LDS16(Ahi + aoff0, AbufH + (size_t)tid * 8);
        GLOAD_LDS16(Ahi + aoff1, AbufH + (size_t)(256 + tid) * 8);
        GLOAD_LDS16(Alo + aoff0, AbufL + (size_t)tid * 8);
        GLOAD_LDS16(Alo + aoff1, AbufL + (size_t)(256 + tid) * 8);
        GLOAD_LDS16(Bhi + boff, BbufH + (size_t)tid * 8);
        GLOAD_LDS16(Blo + boff, BbufL + (size_t)tid * 8);
        __syncthreads();

        bf16x8 afh[2], afl[2], bfh[4], bfl[4];
#pragma unroll
        for (int mi = 0; mi < 2; ++mi) {
            const int ro = (wave * 32 + mi * 16 + fr) * 32 + fk;
            afh[mi] = *(const bf16x8*)(AbufH + ro);
            afl[mi] = *(const bf16x8*)(AbufL + ro);
        }
#pragma unroll
        for (int ni = 0; ni < 4; ++ni) {
            const int ro = (ni * 16 + fr) * 32 + fk;
            bfh[ni] = *(const bf16x8*)(BbufH + ro);
            bfl[ni] = *(const bf16x8*)(BbufL + ro);
        }

#pragma unroll
        for (int mi = 0; mi < 2; ++mi)
#pragma unroll
            for (int ni = 0; ni < 4; ++ni) {
                acc[mi][ni] = __builtin_amdgcn_mfma_f32_16x16x32_bf16(afh[mi], bfl[ni], acc[mi][ni], 0, 0, 0);
                acc[mi][ni] = __builtin_amdgcn_mfma_f32_16x16x32_bf16(afl[mi], bfh[ni], acc[mi][ni], 0, 0, 0);
                acc[mi][ni] = __builtin_amdgcn_mfma_f32_16x16x32_bf16(afh[mi], bfh[ni], acc[mi][ni], 0, 0, 0);
            }
    }

#pragma unroll
    for (int ni = 0; ni < 4; ++ni) {
        const int o = n0 + ni * 16 + (lane & 15);
        const float bv = bias[o];
#pragma unroll
        for (int mi = 0; mi < 2; ++mi) {
#pragma unroll
            for (int reg = 0; reg < 4; ++reg) {
                const int m = m0 + wave * 32 + mi * 16 + ((lane >> 4) << 2) + reg;
                const float v = acc[mi][ni][reg] + bv;
                if (scatter) {
                    const int bb = m >> 11;
                    const int n  = m & 2047;
                    const int h  = o >> 6;
                    const int d  = o & 63;
                    out[(((size_t)(bb * HEADS + h)) * NTOK + n) * DHEAD + d] = v;
                } else {
                    out[(size_t)m * DMODEL + o] = v;
                }
            }
        }
    }
}

// ---------------------------------------------------------------------------
// score_chunk: S[bh, q_local, k] = (Q[bh, q0+q_local, :] . K[bh, k, :]) / 8
// ---------------------------------------------------------------------------
__global__ __launch_bounds__(256) void score_chunk(const float* __restrict__ Q,
                                                   const float* __restrict__ K,
                                                   float* __restrict__ S,
                                                   int q0, int QC)
{
    const int kt = blockIdx.x;
    const int qt = blockIdx.y;
    const int qt_g = (q0 >> 6) + qt;
    if (kt > qt_g) return;
    const int bh = blockIdx.z;

    __shared__ float As[16][65];
    __shared__ float Bs[16][65];

    const int tid = threadIdx.x;
    const int tx = tid & 15;
    const int ty = tid >> 4;
    const int lr = tid >> 2;
    const int lc = (tid & 3) << 2;

    const float* Qb = Q + ((size_t)bh * NTOK + q0 + qt * 64) * DHEAD;
    const float* Kb = K + ((size_t)bh * NTOK + kt * 64) * DHEAD;

    float acc[4][4];
#pragma unroll
    for (int i = 0; i < 4; ++i)
#pragma unroll
        for (int j = 0; j < 4; ++j) acc[i][j] = 0.f;

#pragma unroll
    for (int k0 = 0; k0 < DHEAD; k0 += 16) {
        float4 av = *(const float4*)(Qb + (size_t)lr * DHEAD + k0 + lc);
        float4 bv = *(const float4*)(Kb + (size_t)lr * DHEAD + k0 + lc);
        As[lc + 0][lr] = av.x; As[lc + 1][lr] = av.y;
        As[lc + 2][lr] = av.z; As[lc + 3][lr] = av.w;
        Bs[lc + 0][lr] = bv.x; Bs[lc + 1][lr] = bv.y;
        Bs[lc + 2][lr] = bv.z; Bs[lc + 3][lr] = bv.w;
        __syncthreads();
#pragma unroll
        for (int kk = 0; kk < 16; ++kk) {
            float a0 = As[kk][ty * 4 + 0];
            float a1 = As[kk][ty * 4 + 1];
            float a2 = As[kk][ty * 4 + 2];
            float a3 = As[kk][ty * 4 + 3];
            float b0 = Bs[kk][tx * 4 + 0];
            float b1 = Bs[kk][tx * 4 + 1];
            float b2 = Bs[kk][tx * 4 + 2];
            float b3 = Bs[kk][tx * 4 + 3];
            acc[0][0] += a0 * b0; acc[0][1] += a0 * b1; acc[0][2] += a0 * b2; acc[0][3] += a0 * b3;
            acc[1][0] += a1 * b0; acc[1][1] += a1 * b1; acc[1][2] += a1 * b2; acc[1][3] += a1 * b3;
            acc[2][0] += a2 * b0; acc[2][1] += a2 * b1; acc[2][2] += a2 * b2; acc[2][3] += a2 * b3;
            acc[3][0] += a3 * b0; acc[3][1] += a3 * b1; acc[3][2] += a3 * b2; acc[3][3] += a3 * b3;
        }
        __syncthreads();
    }

#pragma unroll
    for (int i = 0; i < 4; ++i) {
        const int ql = qt * 64 + ty * 4 + i;
        float* Srow = S + ((size_t)bh * QC + ql) * NTOK;
#pragma unroll
        for (int j = 0; j < 4; ++j) {
            const int k = kt * 64 + tx * 4 + j;
            Srow[k] = acc[i][j] * 0.125f;
        }
    }
}

// ---------------------------------------------------------------------------
// select_v4: ballot-threshold top-k. One wave per (q,h). Binary search the
// monotone key space for the nsel-th value using per-slot __ballot counts
// (scalar-pipe reduction, no shuffle chains). Exact top_k tie semantics
// (smallest indices) via rare index-search slow path. Compaction to LDS
// for the AV gather. Selection set bit-identical to v2/v3.
// ---------------------------------------------------------------------------
__device__ __forceinline__ unsigned mono_key(float f) {
    const unsigned u = __float_as_uint(f);
    return (u ^ (unsigned)(((int)u >> 31) | 0x80000000)) + 1u;
}
__device__ __forceinline__ float unmono(unsigned m) {
    const unsigned u = m - 1u;
    return __uint_as_float(u ^ (unsigned)(((int)(~u) >> 31) | 0x80000000));
}

template<int SLOTS>
__device__ __forceinline__ void select_task(const float* __restrict__ Srow,
                                            const float* __restrict__ Vb,
                                            float* __restrict__ ctxRow,
                                            float* __restrict__ attnRow,
                                            int L, int nsel,
                                            int* __restrict__ sIdx,
                                            float* __restrict__ sE)
{
    const int lane = threadIdx.x & 63;

    // ---- load scores -> monotone keys (0 = empty)
    unsigned km[SLOTS];
    unsigned lmax = 0u;
#pragma unroll
    for (int s = 0; s < SLOTS; ++s) {
        const int j = s * 64 + lane;
        unsigned m = 0u;
        if (j < L) m = mono_key(Srow[j]);
        km[s] = m;
        lmax = (m > lmax) ? m : lmax;
    }

    // ---- wave max key (softmax max + search upper bound)
    unsigned gmax = lmax;
#pragma unroll
    for (int d = 1; d < 64; d <<= 1) {
        const unsigned o = __shfl_xor(gmax, d, 64);
        gmax = (o > gmax) ? o : gmax;
    }

    // ---- binary search: largest T in [1, gmax] with count(key >= T) >= nsel
    unsigned lo = 1u, hi = gmax;
    while (lo < hi) {
        const unsigned mid = lo + ((hi - lo + 1u) >> 1);
        int cnt = 0;
#pragma unroll
        for (int s = 0; s < SLOTS; ++s)
            cnt += __popcll(__ballot(km[s] >= mid));
        if (cnt >= nsel) lo = mid; else hi = mid - 1u;
    }
    const unsigned T = lo;

    int cnt_ge = 0, cnt_gt = 0;
#pragma unroll
    for (int s = 0; s < SLOTS; ++s) {
        cnt_ge += __popcll(__ballot(km[s] >= T));
        cnt_gt += __popcll(__ballot(km[s] > T));
    }

    unsigned selmask = 0u;
    if (cnt_ge == nsel) {
        // fast path: no duplicate-value boundary
#pragma unroll
        for (int s = 0; s < SLOTS; ++s)
            selmask |= (km[s] >= T) ? (1u << s) : 0u;
    } else {
        // slow path: take k_tie smallest-index elements among km == T
        const int k_tie = nsel - cnt_gt;
        unsigned tiemask = 0u;
#pragma unroll
        for (int s = 0; s < SLOTS; ++s)
            tiemask |= (km[s] == T) ? (1u << s) : 0u;
        // smallest C in [1, L] with (#ties idx < C) >= k_tie
        int clo = 1, chi = L;
        while (clo < chi) {
            const int cmid = (clo + chi) >> 1;
            int sm = (cmid - lane + 63) >> 6;
            sm = (sm < 0) ? 0 : ((sm > SLOTS) ? SLOTS : sm);
            const unsigned mm = (sm >= 32) ? 0xFFFFFFFFu : ((1u << sm) - 1u);
            const int c = __popc(tiemask & mm);
            int tot = 0;
#pragma unroll
            for (int b = 0; b < 6; ++b)
                tot += __popcll(__ballot((c >> b) & 1)) << b;
            if (tot >= k_tie) chi = cmid; else clo = cmid + 1;
        }
        const int C = clo;
#pragma unroll
        for (int s = 0; s < SLOTS; ++s) {
            const int j = s * 64 + lane;
            const bool sel = (km[s] > T) || ((km[s] == T) && (j < C));
            selmask |= sel ? (1u << s) : 0u;
        }
    }

    // ---- compaction prefix (exclusive) of per-lane selected counts
    const int c = __popc(selmask);
    int pfx = c;
#pragma unroll
    for (int d = 1; d < 64; d <<= 1) {
        const int t = __shfl_up(pfx, d, 64);
        if (lane >= d) pfx += t;
    }
    pfx -= c;

    // ---- exp + LDS compaction
    const float vmax = unmono(gmax);
    float esum = 0.f;
    unsigned msk = selmask;
    int pos = pfx;
    while (msk) {
        const int s = __builtin_ctz(msk);
        msk &= msk - 1u;
        const int j = s * 64 + lane;
        const float e = __expf(unmono(km[s]) - vmax);
        esum += e;
        sIdx[pos] = j;
        sE[pos] = e;
        ++pos;
    }

    // ---- Z (wave sum)
    float Z = esum;
#pragma unroll
    for (int d = 1; d < 64; d <<= 1) Z += __shfl_xor(Z, d, 64);
    const float rcpZ = 1.0f / Z;

    // ---- attn-mean atomics (attn pre-zeroed)
    msk = selmask;
    pos = pfx;
    while (msk) {
        const int s = __builtin_ctz(msk);
        msk &= msk - 1u;
        const int j = s * 64 + lane;
        const float w = sE[pos] * rcpZ;
        ++pos;
        atomicAdd(&attnRow[j], w * (1.0f / (float)HEADS));
    }

    // ---- ctx[d=lane] = sum_i w_i * V[idx_i, lane]
    float acc = 0.f;
    for (int i = 0; i < nsel; ++i) {
        const int idx = sIdx[i];
        const float wi = sE[i] * rcpZ;
        acc += wi * Vb[(size_t)idx * DHEAD + lane];
    }
    ctxRow[lane] = acc;
}

__global__ __launch_bounds__(256) void select_v4(const float* __restrict__ S,
                                                 const float* __restrict__ V,
                                                 float* __restrict__ ctx,
                                                 float* __restrict__ attn,
                                                 int q0, int QC)
{
    __shared__ int   sIdxAll[4][KSEL];
    __shared__ float sEAll[4][KSEL];

    const int wave = threadIdx.x >> 6;
    const int ql = blockIdx.x;
    const int b  = blockIdx.y >> 2;
    const int hg = blockIdx.y & 3;
    const int h  = hg * 4 + wave;
    const int q  = q0 + ql;
    const int L = q + 1;
    const int nsel = (L < KSEL) ? L : KSEL;

    const size_t bh = (size_t)(b * HEADS + h);
    const float* Srow = S + (bh * QC + ql) * NTOK;
    const float* Vb   = V + bh * NTOK * DHEAD;
    float* ctxRow  = ctx + (((size_t)(b * NTOK + q)) * HEADS + h) * DHEAD;
    float* attnRow = attn + ((size_t)(b * NTOK + q)) * NTOK;

    if (q < 512)       select_task<8 >(Srow, Vb, ctxRow, attnRow, L, nsel, sIdxAll[wave], sEAll[wave]);
    else if (q < 1024) select_task<16>(Srow, Vb, ctxRow, attnRow, L, nsel, sIdxAll[wave], sEAll[wave]);
    else               select_task<32>(Srow, Vb, ctxRow, attnRow, L, nsel, sIdxAll[wave], sEAll[wave]);
}

// ---------------------------------------------------------------------------
// Fallback fused attention — only if ws can't fit a QC=64 score chunk.
// ---------------------------------------------------------------------------
__global__ __launch_bounds__(256) void attn_kernel(const float* __restrict__ Q,
                                                   const float* __restrict__ K,
                                                   const float* __restrict__ V,
                                                   float* __restrict__ ctx,
                                                   float* __restrict__ attn_out)
{
    const int blk = blockIdx.x;
    const int b = blk >> 11;
    const int q = blk & (NTOK - 1);
    const int tid = threadIdx.x;
    const int wave = tid >> 6;
    const int lane = tid & 63;

    __shared__ float sc[4][NTOK];
    __shared__ float am[NTOK];
    __shared__ float selv[4][KSEL];
    __shared__ int   seli[4][KSEL];
    __shared__ float selw[4][KSEL];

    for (int j = tid; j < NTOK; j += 256) am[j] = 0.f;
    __syncthreads();

    const int L = q + 1;
    const int nsel = (L < KSEL) ? L : KSEL;

    for (int hg = 0; hg < 4; ++hg) {
        const int h = hg * 4 + wave;
        const size_t bh = (size_t)(b * HEADS + h);
        const float* Qrow = Q + (bh * NTOK + q) * DHEAD;
        const float* Kb = K + bh * NTOK * DHEAD;
        const float* Vb = V + bh * NTOK * DHEAD;

        float4 qr[16];
#pragma unroll
        for (int d4 = 0; d4 < 16; ++d4) qr[d4] = ((const float4*)Qrow)[d4];

        float lm = -INFINITY; int li = -1;
        for (int j = lane; j < L; j += 64) {
            const float4* kr = (const float4*)(Kb + (size_t)j * DHEAD);
            float a0 = 0.f, a1 = 0.f, a2 = 0.f, a3 = 0.f;
#pragma unroll
            for (int d4 = 0; d4 < 16; ++d4) {
                const float4 kk = kr[d4];
                a0 += qr[d4].x * kk.x;
                a1 += qr[d4].y * kk.y;
                a2 += qr[d4].z * kk.z;
                a3 += qr[d4].w * kk.w;
            }
            const float s = (a0 + a1 + a2 + a3) * 0.125f;
            sc[wave][j] = s;
            if (s > lm) { lm = s; li = j; }
        }

        for (int it = 0; it < nsel; ++it) {
            float bmv = lm; int bi = li;
#pragma unroll
            for (int mask = 1; mask < 64; mask <<= 1) {
                const float ov = __shfl_xor(bmv, mask, 64);
                const int   oi = __shfl_xor(bi, mask, 64);
                if (ov > bmv || (ov == bmv && (unsigned)oi < (unsigned)bi)) {
                    bmv = ov; bi = oi;
                }
            }
            if (lane == (bi & 63)) {
                sc[wave][bi] = -INFINITY;
                lm = -INFINITY; li = -1;
                for (int j = lane; j < L; j += 64) {
                    const float s = sc[wave][j];
                    if (s > lm) { lm = s; li = j; }
                }
            }
            if (lane == 0) { selv[wave][it] = bmv; seli[wave][it] = bi; }
        }

        const float m = selv[wave][0];
        float e = 0.f;
        if (lane < nsel) e = expf(selv[wave][lane] - m);
        float Z = e;
#pragma unroll
        for (int mask = 1; mask < 32; mask <<= 1) Z += __shfl_xor(Z, mask, 64);
        if (lane < nsel) {
            const float w = e / Z;
            selw[wave][lane] = w;
            atomicAdd(&am[seli[wave][lane]], w);
        }

        float acc = 0.f;
        for (int i = 0; i < nsel; ++i) {
            const int idx = seli[wave][i];
            const float w = selw[wave][i];
            acc += w * Vb[(size_t)idx * DHEAD + lane];
        }
        ctx[(((size_t)(b * NTOK + q)) * HEADS + h) * DHEAD + lane] = acc;
    }

    __syncthreads();
    const float invH = 1.0f / (float)HEADS;
    float* arow = attn_out + ((size_t)(b * NTOK + q)) * NTOK;
    for (int j = tid; j < NTOK; j += 256) arow[j] = am[j] * invH;
}

// ---------------------------------------------------------------------------
extern "C" void kernel_launch(void* const* d_in, const int* in_sizes, int n_in,
                              void* d_out, int out_size, void* d_ws, size_t ws_size,
                              hipStream_t stream) {
    const float* x  = (const float*)d_in[0];
    const float* Wq = (const float*)d_in[1];
    const float* bq = (const float*)d_in[2];
    const float* Wk = (const float*)d_in[3];
    const float* bk = (const float*)d_in[4];
    const float* Wv = (const float*)d_in[5];
    const float* bv = (const float*)d_in[6];
    const float* Wo = (const float*)d_in[7];
    const float* bo = (const float*)d_in[8];

    const size_t MB = 1ull << 20;
    char* wsb = (char*)d_ws;
    float* Qws = (float*)(wsb + 0 * MB);
    float* Kws = (float*)(wsb + 16 * MB);
    float* Vws = (float*)(wsb + 32 * MB);
    float* ctx = (float*)(wsb + 48 * MB);
    ushort_t* xhi = (ushort_t*)(wsb + 64 * MB);
    ushort_t* xlo = (ushort_t*)(wsb + 72 * MB);
    ushort_t* wqh = (ushort_t*)(wsb + 80 * MB);
    ushort_t* wql = (ushort_t*)(wsb + 82 * MB);
    ushort_t* wkh = (ushort_t*)(wsb + 84 * MB);
    ushort_t* wkl = (ushort_t*)(wsb + 86 * MB);
    ushort_t* wvh = (ushort_t*)(wsb + 88 * MB);
    ushort_t* wvl = (ushort_t*)(wsb + 90 * MB);
    ushort_t* woh = (ushort_t*)(wsb + 92 * MB);
    ushort_t* wol = (ushort_t*)(wsb + 94 * MB);
    ushort_t* cxh = xhi;   // reuse (x dead after QKV)
    ushort_t* cxl = xlo;
    float*    Sws = (float*)(wsb + 96 * MB);

    float* y    = (float*)d_out;
    float* attn = y + (size_t)BATCH * NTOK * DMODEL;

    const int NX = MROWS * DMODEL;
    const int NW = DMODEL * DMODEL;

    // ---- bf16 split conversions
    conv_split<<<NX / (256 * 4), 256, 0, stream>>>(x, xhi, xlo, NX);
    conv_split<<<NW / (256 * 4), 256, 0, stream>>>(Wq, wqh, wql, NW);
    conv_split<<<NW / (256 * 4), 256, 0, stream>>>(Wk, wkh, wkl, NW);
    conv_split<<<NW / (256 * 4), 256, 0, stream>>>(Wv, wvh, wvl, NW);
    conv_split<<<NW / (256 * 4), 256, 0, stream>>>(Wo, woh, wol, NW);

    // ---- Q/K/V projections (split-bf16 MFMA)
    dim3 ggrid(MROWS / 128, DMODEL / 64);
    gemm_split_mfma<<<ggrid, 256, 0, stream>>>(xhi, xlo, wqh, wql, bq, Qws, 1);
    gemm_split_mfma<<<ggrid, 256, 0, stream>>>(xhi, xlo, wkh, wkl, bk, Kws, 1);
    gemm_split_mfma<<<ggrid, 256, 0, stream>>>(xhi, xlo, wvh, wvl, bv, Vws, 1);

    // ---- attention
    const size_t base_bytes = 96 * MB;
    const size_t avail = (ws_size > base_bytes) ? ws_size - base_bytes : 0;
    int QC = 0;
    for (int cand = NTOK; cand >= 64; cand >>= 1) {
        const size_t need = (size_t)BATCH * HEADS * cand * NTOK * sizeof(float);
        if (need <= avail) { QC = cand; break; }
    }

    if (QC > 0) {
        const int nattn4 = BATCH * NTOK * NTOK / 4;
        zero_fill<<<(nattn4 + 255) / 256, 256, 0, stream>>>(attn, nattn4);
        for (int q0 = 0; q0 < NTOK; q0 += QC) {
            dim3 sgrid((q0 + QC) / 64, QC / 64, BATCH * HEADS);
            score_chunk<<<sgrid, 256, 0, stream>>>(Qws, Kws, Sws, q0, QC);
            dim3 selgrid(QC, BATCH * 4);
            select_v4<<<selgrid, 256, 0, stream>>>(Sws, Vws, ctx, attn, q0, QC);
        }
    } else {
        attn_kernel<<<BATCH * NTOK, 256, 0, stream>>>(Qws, Kws, Vws, ctx, attn);
    }

    // ---- output projection (split-bf16 MFMA)
    conv_split<<<NX / (256 * 4), 256, 0, stream>>>(ctx, cxh, cxl, NX);
    gemm_split_mfma<<<ggrid, 256, 0, stream>>>(cxh, cxl, woh, wol, bo, y, 0);
}

// Round 9
// 645.334 us; speedup vs baseline: 5.0955x; 1.1883x over previous
//
#include <hip/hip_runtime.h>
#include <hip/hip_bf16.h>
#include <math.h>

// Problem constants
#define BATCH   2
#define NTOK    2048
#define DMODEL  1024
#define HEADS   16
#define DHEAD   64
#define KSEL    32
#define MROWS   (BATCH * NTOK)   // 4096

typedef short     bf16x8 __attribute__((ext_vector_type(8)));
typedef float     f32x4  __attribute__((ext_vector_type(4)));
typedef unsigned short ushort_t;
typedef unsigned long long u64;

#define GLOAD_LDS16(g, l) \
    __builtin_amdgcn_global_load_lds((const __attribute__((address_space(1))) void*)(g), \
                                     (__attribute__((address_space(3))) void*)(l), 16, 0, 0)

// ---------------------------------------------------------------------------
// f32 -> (hi, lo) bf16 split: hi = bf16(x), lo = bf16(x - hi)
// ---------------------------------------------------------------------------
__device__ __forceinline__ ushort_t f2bf(float f) {
    unsigned u = __float_as_uint(f);
    unsigned r = (u + 0x7FFFu + ((u >> 16) & 1u)) >> 16;
    return (ushort_t)r;
}
__device__ __forceinline__ float bf2f(ushort_t h) {
    return __uint_as_float(((unsigned)h) << 16);
}

__global__ __launch_bounds__(256) void conv_split(const float* __restrict__ in,
                                                  ushort_t* __restrict__ hi,
                                                  ushort_t* __restrict__ lo, int n)
{
    const int i = (blockIdx.x * 256 + threadIdx.x) * 4;
    if (i + 3 < n) {
        const float4 v = *(const float4*)(in + i);
        ushort4 ph, pl;
        ph.x = f2bf(v.x); pl.x = f2bf(v.x - bf2f(ph.x));
        ph.y = f2bf(v.y); pl.y = f2bf(v.y - bf2f(ph.y));
        ph.z = f2bf(v.z); pl.z = f2bf(v.z - bf2f(ph.z));
        ph.w = f2bf(v.w); pl.w = f2bf(v.w - bf2f(ph.w));
        *(ushort4*)(hi + i) = ph;
        *(ushort4*)(lo + i) = pl;
    }
}

__global__ __launch_bounds__(256) void zero_fill(float* __restrict__ p, int n4)
{
    const int i = blockIdx.x * 256 + threadIdx.x;
    if (i < n4) ((float4*)p)[i] = (float4){0.f, 0.f, 0.f, 0.f};
}

// ---------------------------------------------------------------------------
// monotone key <-> float (bijective; order-preserving; 0 reserved for empty)
// ---------------------------------------------------------------------------
__device__ __forceinline__ unsigned mono_key(float f) {
    const unsigned u = __float_as_uint(f);
    return (u ^ (unsigned)(((int)u >> 31) | 0x80000000)) + 1u;
}
__device__ __forceinline__ float unmono(unsigned m) {
    const unsigned u = m - 1u;
    return __uint_as_float(u ^ (unsigned)(((int)(~u) >> 31) | 0x80000000));
}

// ---------------------------------------------------------------------------
// Split-bf16 MFMA GEMM: C = A*B^T + bias (fp32-class accuracy via 3 MFMAs)
// ---------------------------------------------------------------------------
__global__ __launch_bounds__(256) void gemm_split_mfma(const ushort_t* __restrict__ Ahi,
                                                       const ushort_t* __restrict__ Alo,
                                                       const ushort_t* __restrict__ Bhi,
                                                       const ushort_t* __restrict__ Blo,
                                                       const float* __restrict__ bias,
                                                       float* __restrict__ out,
                                                       int scatter)
{
    __shared__ ushort_t AbufH[128 * 32];
    __shared__ ushort_t AbufL[128 * 32];
    __shared__ ushort_t BbufH[64 * 32];
    __shared__ ushort_t BbufL[64 * 32];

    const int tid  = threadIdx.x;
    const int wave = tid >> 6;
    const int lane = tid & 63;
    const int m0 = blockIdx.x * 128;
    const int n0 = blockIdx.y * 64;

    f32x4 acc[2][4];
#pragma unroll
    for (int i = 0; i < 2; ++i)
#pragma unroll
        for (int j = 0; j < 4; ++j) acc[i][j] = (f32x4){0.f, 0.f, 0.f, 0.f};

    const int ar0 = tid >> 2;
    const int ar1 = 64 + (tid >> 2);
    const int ak  = (tid & 3) << 3;
    const int br  = tid >> 2;

    const int fr = lane & 15;
    const int fk = (lane >> 4) << 3;

    for (int k0 = 0; k0 < DMODEL; k0 += 32) {
        __syncthreads();
        const size_t aoff0 = (size_t)(m0 + ar0) * DMODEL + k0 + ak;
        const size_t aoff1 = (size_t)(m0 + ar1) * DMODEL + k0 + ak;
        const size_t boff  = (size_t)(n0 + br) * DMODEL + k0 + ak;
        GLOAD_LDS16(Ahi + aoff0, AbufH + (size_t)tid * 8);
        GLOAD_LDS16(Ahi + aoff1, AbufH + (size_t)(256 + tid) * 8);
        GLOAD_LDS16(Alo + aoff0, AbufL + (size_t)tid * 8);
        GLOAD_LDS16(Alo + aoff1, AbufL + (size_t)(256 + tid) * 8);
        GLOAD_LDS16(Bhi + boff, BbufH + (size_t)tid * 8);
        GLOAD_LDS16(Blo + boff, BbufL + (size_t)tid * 8);
        __syncthreads();

        bf16x8 afh[2], afl[2], bfh[4], bfl[4];
#pragma unroll
        for (int mi = 0; mi < 2; ++mi) {
            const int ro = (wave * 32 + mi * 16 + fr) * 32 + fk;
            afh[mi] = *(const bf16x8*)(AbufH + ro);
            afl[mi] = *(const bf16x8*)(AbufL + ro);
        }
#pragma unroll
        for (int ni = 0; ni < 4; ++ni) {
            const int ro = (ni * 16 + fr) * 32 + fk;
            bfh[ni] = *(const bf16x8*)(BbufH + ro);
            bfl[ni] = *(const bf16x8*)(BbufL + ro);
        }

#pragma unroll
        for (int mi = 0; mi < 2; ++mi)
#pragma unroll
            for (int ni = 0; ni < 4; ++ni) {
                acc[mi][ni] = __builtin_amdgcn_mfma_f32_16x16x32_bf16(afh[mi], bfl[ni], acc[mi][ni], 0, 0, 0);
                acc[mi][ni] = __builtin_amdgcn_mfma_f32_16x16x32_bf16(afl[mi], bfh[ni], acc[mi][ni], 0, 0, 0);
                acc[mi][ni] = __builtin_amdgcn_mfma_f32_16x16x32_bf16(afh[mi], bfh[ni], acc[mi][ni], 0, 0, 0);
            }
    }

#pragma unroll
    for (int ni = 0; ni < 4; ++ni) {
        const int o = n0 + ni * 16 + (lane & 15);
        const float bv = bias[o];
#pragma unroll
        for (int mi = 0; mi < 2; ++mi) {
#pragma unroll
            for (int reg = 0; reg < 4; ++reg) {
                const int m = m0 + wave * 32 + mi * 16 + ((lane >> 4) << 2) + reg;
                const float v = acc[mi][ni][reg] + bv;
                if (scatter) {
                    const int bb = m >> 11;
                    const int n  = m & 2047;
                    const int h  = o >> 6;
                    const int d  = o & 63;
                    out[(((size_t)(bb * HEADS + h)) * NTOK + n) * DHEAD + d] = v;
                } else {
                    out[(size_t)m * DMODEL + o] = v;
                }
            }
        }
    }
}

// ---------------------------------------------------------------------------
// score_chunk: writes MONOTONE U32 KEYS of (Q.K)/8 — select consumes keys
// directly; exact fp32 value is recovered bijectively via unmono().
// ---------------------------------------------------------------------------
__global__ __launch_bounds__(256) void score_chunk(const float* __restrict__ Q,
                                                   const float* __restrict__ K,
                                                   unsigned* __restrict__ S,
                                                   int q0, int QC)
{
    const int kt = blockIdx.x;
    const int qt = blockIdx.y;
    const int qt_g = (q0 >> 6) + qt;
    if (kt > qt_g) return;
    const int bh = blockIdx.z;

    __shared__ float As[16][65];
    __shared__ float Bs[16][65];

    const int tid = threadIdx.x;
    const int tx = tid & 15;
    const int ty = tid >> 4;
    const int lr = tid >> 2;
    const int lc = (tid & 3) << 2;

    const float* Qb = Q + ((size_t)bh * NTOK + q0 + qt * 64) * DHEAD;
    const float* Kb = K + ((size_t)bh * NTOK + kt * 64) * DHEAD;

    float acc[4][4];
#pragma unroll
    for (int i = 0; i < 4; ++i)
#pragma unroll
        for (int j = 0; j < 4; ++j) acc[i][j] = 0.f;

#pragma unroll
    for (int k0 = 0; k0 < DHEAD; k0 += 16) {
        float4 av = *(const float4*)(Qb + (size_t)lr * DHEAD + k0 + lc);
        float4 bv = *(const float4*)(Kb + (size_t)lr * DHEAD + k0 + lc);
        As[lc + 0][lr] = av.x; As[lc + 1][lr] = av.y;
        As[lc + 2][lr] = av.z; As[lc + 3][lr] = av.w;
        Bs[lc + 0][lr] = bv.x; Bs[lc + 1][lr] = bv.y;
        Bs[lc + 2][lr] = bv.z; Bs[lc + 3][lr] = bv.w;
        __syncthreads();
#pragma unroll
        for (int kk = 0; kk < 16; ++kk) {
            float a0 = As[kk][ty * 4 + 0];
            float a1 = As[kk][ty * 4 + 1];
            float a2 = As[kk][ty * 4 + 2];
            float a3 = As[kk][ty * 4 + 3];
            float b0 = Bs[kk][tx * 4 + 0];
            float b1 = Bs[kk][tx * 4 + 1];
            float b2 = Bs[kk][tx * 4 + 2];
            float b3 = Bs[kk][tx * 4 + 3];
            acc[0][0] += a0 * b0; acc[0][1] += a0 * b1; acc[0][2] += a0 * b2; acc[0][3] += a0 * b3;
            acc[1][0] += a1 * b0; acc[1][1] += a1 * b1; acc[1][2] += a1 * b2; acc[1][3] += a1 * b3;
            acc[2][0] += a2 * b0; acc[2][1] += a2 * b1; acc[2][2] += a2 * b2; acc[2][3] += a2 * b3;
            acc[3][0] += a3 * b0; acc[3][1] += a3 * b1; acc[3][2] += a3 * b2; acc[3][3] += a3 * b3;
        }
        __syncthreads();
    }

#pragma unroll
    for (int i = 0; i < 4; ++i) {
        const int ql = qt * 64 + ty * 4 + i;
        unsigned* Srow = S + ((size_t)bh * QC + ql) * NTOK;
#pragma unroll
        for (int j = 0; j < 4; ++j) {
            const int k = kt * 64 + tx * 4 + j;
            Srow[k] = mono_key(acc[i][j] * 0.125f);
        }
    }
}

// ---------------------------------------------------------------------------
// select_v5: 16-bit-granular ballot threshold search on u32 mono keys.
// Threshold candidates are multiples of 2^16 -> <=16 iterations, seeded by
// [min-of-lane-maxima, gmax]. Boundary (same hi-16 prefix) resolved exactly
// with full keys via serial u64 extraction. Selection + softmax values
// bit-identical to v2/v3/v4.
// ---------------------------------------------------------------------------
template<int SLOTS>
__device__ __forceinline__ void select_task(const unsigned* __restrict__ Srow,
                                            const float* __restrict__ Vb,
                                            float* __restrict__ ctxRow,
                                            float* __restrict__ attnRow,
                                            int L, int nsel,
                                            int* __restrict__ sIdx,
                                            float* __restrict__ sE)
{
    const int lane = threadIdx.x & 63;

    // ---- load keys (0 = empty); track per-lane max
    unsigned km[SLOTS];
    unsigned lmax = 0u;
#pragma unroll
    for (int s = 0; s < SLOTS; ++s) {
        const int j = s * 64 + lane;
        unsigned m = 0u;
        if (j < L) m = Srow[j];
        km[s] = m;
        lmax = (m > lmax) ? m : lmax;
    }

    // ---- wave max + wave min-of-lane-maxima (one butterfly, both ops)
    unsigned gmax = lmax, mmin = lmax;
#pragma unroll
    for (int d = 1; d < 64; d <<= 1) {
        const unsigned o1 = __shfl_xor(gmax, d, 64);
        const unsigned o2 = __shfl_xor(mmin, d, 64);
        gmax = (o1 > gmax) ? o1 : gmax;
        mmin = (o2 < mmin) ? o2 : mmin;
    }

    // ---- binary search over hi-16 prefixes: largest T16 with
    //      count(km >= T16<<16) >= nsel.  lo seed feasible iff all lanes
    //      non-empty (L >= 64): count(>= mmin) >= 64 >= nsel.
    unsigned lo = (L >= 64) ? (mmin >> 16) : 1u;
    if (lo < 1u) lo = 1u;
    unsigned hi = gmax >> 16;
    while (lo < hi) {
        const unsigned mid = lo + ((hi - lo + 1u) >> 1);
        const unsigned midk = mid << 16;
        int cnt = 0;
#pragma unroll
        for (int s = 0; s < SLOTS; ++s)
            cnt += __popcll(__ballot(km[s] >= midk));
        if (cnt >= nsel) lo = mid; else hi = mid - 1u;
    }
    const unsigned Tk  = lo << 16;            // boundary group: [Tk, Tk+2^16)
    const unsigned Gk  = Tk | 0xFFFFu;        // km > Gk  <=>  km16 > T16

    int cnt_ge = 0, cnt_gt = 0;
#pragma unroll
    for (int s = 0; s < SLOTS; ++s) {
        cnt_ge += __popcll(__ballot(km[s] >= Tk));
        cnt_gt += __popcll(__ballot(km[s] > Gk));
    }

    unsigned selmask = 0u;
    if (cnt_ge == nsel) {
        // no boundary ambiguity at 16-bit granularity
#pragma unroll
        for (int s = 0; s < SLOTS; ++s)
            selmask |= (km[s] >= Tk) ? (1u << s) : 0u;
    } else {
        // definite winners + k_tie best-of-boundary by full key desc / idx asc
        unsigned bmask = 0u;
#pragma unroll
        for (int s = 0; s < SLOTS; ++s) {
            selmask |= (km[s] > Gk) ? (1u << s) : 0u;
            bmask   |= (km[s] >= Tk && km[s] <= Gk) ? (1u << s) : 0u;
        }
        int k_tie = nsel - cnt_gt;
        while (k_tie > 0) {
            // per-lane best remaining boundary candidate
            u64 best = 0;
            unsigned bm = bmask;
            int bs = -1;
            while (bm) {
                const int s = __builtin_ctz(bm);
                bm &= bm - 1u;
                const u64 k = ((u64)km[s] << 32) | (unsigned)~(s * 64 + lane);
                if (k > best) { best = k; bs = s; }
            }
            u64 b = best;
#pragma unroll
            for (int d = 1; d < 64; d <<= 1) {
                const u64 o = __shfl_xor(b, d, 64);
                b = (o > b) ? o : b;
            }
            const unsigned gidx = ~(unsigned)b;
            if (lane == (int)(gidx & 63u)) {
                const unsigned bit = 1u << (gidx >> 6);
                selmask |= bit;
                bmask &= ~bit;
            }
            --k_tie;
        }
    }

    // ---- exclusive prefix of per-lane selected counts
    const int c = __popc(selmask);
    int pfx = c;
#pragma unroll
    for (int d = 1; d < 64; d <<= 1) {
        const int t = __shfl_up(pfx, d, 64);
        if (lane >= d) pfx += t;
    }
    pfx -= c;

    // ---- exp + LDS compaction (vmax = exact value of global max key)
    const float vmax = unmono(gmax);
    float esum = 0.f;
    unsigned msk = selmask;
    int pos = pfx;
    while (msk) {
        const int s = __builtin_ctz(msk);
        msk &= msk - 1u;
        const int j = s * 64 + lane;
        const float e = __expf(unmono(km[s]) - vmax);
        esum += e;
        sIdx[pos] = j;
        sE[pos] = e;
        ++pos;
    }

    // ---- Z (wave sum)
    float Z = esum;
#pragma unroll
    for (int d = 1; d < 64; d <<= 1) Z += __shfl_xor(Z, d, 64);
    const float rcpZ = 1.0f / Z;

    // ---- attn-mean atomics (attn pre-zeroed)
    msk = selmask;
    pos = pfx;
    while (msk) {
        const int s = __builtin_ctz(msk);
        msk &= msk - 1u;
        const int j = s * 64 + lane;
        const float w = sE[pos] * rcpZ;
        ++pos;
        atomicAdd(&attnRow[j], w * (1.0f / (float)HEADS));
    }

    // ---- ctx[d=lane] = sum_i w_i * V[idx_i, lane]
    float acc = 0.f;
    for (int i = 0; i < nsel; ++i) {
        const int idx = sIdx[i];
        const float wi = sE[i] * rcpZ;
        acc += wi * Vb[(size_t)idx * DHEAD + lane];
    }
    ctxRow[lane] = acc;
}

__global__ __launch_bounds__(256) void select_v5(const unsigned* __restrict__ S,
                                                 const float* __restrict__ V,
                                                 float* __restrict__ ctx,
                                                 float* __restrict__ attn,
                                                 int q0, int QC)
{
    __shared__ int   sIdxAll[4][KSEL];
    __shared__ float sEAll[4][KSEL];

    const int wave = threadIdx.x >> 6;
    const int ql = blockIdx.x;
    const int b  = blockIdx.y >> 2;
    const int hg = blockIdx.y & 3;
    const int h  = hg * 4 + wave;
    const int q  = q0 + ql;
    const int L = q + 1;
    const int nsel = (L < KSEL) ? L : KSEL;

    const size_t bh = (size_t)(b * HEADS + h);
    const unsigned* Srow = S + (bh * QC + ql) * NTOK;
    const float* Vb   = V + bh * NTOK * DHEAD;
    float* ctxRow  = ctx + (((size_t)(b * NTOK + q)) * HEADS + h) * DHEAD;
    float* attnRow = attn + ((size_t)(b * NTOK + q)) * NTOK;

    if (q < 512)       select_task<8 >(Srow, Vb, ctxRow, attnRow, L, nsel, sIdxAll[wave], sEAll[wave]);
    else if (q < 1024) select_task<16>(Srow, Vb, ctxRow, attnRow, L, nsel, sIdxAll[wave], sEAll[wave]);
    else               select_task<32>(Srow, Vb, ctxRow, attnRow, L, nsel, sIdxAll[wave], sEAll[wave]);
}

// ---------------------------------------------------------------------------
// Fallback fused attention — only if ws can't fit a QC=64 score chunk.
// ---------------------------------------------------------------------------
__global__ __launch_bounds__(256) void attn_kernel(const float* __restrict__ Q,
                                                   const float* __restrict__ K,
                                                   const float* __restrict__ V,
                                                   float* __restrict__ ctx,
                                                   float* __restrict__ attn_out)
{
    const int blk = blockIdx.x;
    const int b = blk >> 11;
    const int q = blk & (NTOK - 1);
    const int tid = threadIdx.x;
    const int wave = tid >> 6;
    const int lane = tid & 63;

    __shared__ float sc[4][NTOK];
    __shared__ float am[NTOK];
    __shared__ float selv[4][KSEL];
    __shared__ int   seli[4][KSEL];
    __shared__ float selw[4][KSEL];

    for (int j = tid; j < NTOK; j += 256) am[j] = 0.f;
    __syncthreads();

    const int L = q + 1;
    const int nsel = (L < KSEL) ? L : KSEL;

    for (int hg = 0; hg < 4; ++hg) {
        const int h = hg * 4 + wave;
        const size_t bh = (size_t)(b * HEADS + h);
        const float* Qrow = Q + (bh * NTOK + q) * DHEAD;
        const float* Kb = K + bh * NTOK * DHEAD;
        const float* Vb = V + bh * NTOK * DHEAD;

        float4 qr[16];
#pragma unroll
        for (int d4 = 0; d4 < 16; ++d4) qr[d4] = ((const float4*)Qrow)[d4];

        float lm = -INFINITY; int li = -1;
        for (int j = lane; j < L; j += 64) {
            const float4* kr = (const float4*)(Kb + (size_t)j * DHEAD);
            float a0 = 0.f, a1 = 0.f, a2 = 0.f, a3 = 0.f;
#pragma unroll
            for (int d4 = 0; d4 < 16; ++d4) {
                const float4 kk = kr[d4];
                a0 += qr[d4].x * kk.x;
                a1 += qr[d4].y * kk.y;
                a2 += qr[d4].z * kk.z;
                a3 += qr[d4].w * kk.w;
            }
            const float s = (a0 + a1 + a2 + a3) * 0.125f;
            sc[wave][j] = s;
            if (s > lm) { lm = s; li = j; }
        }

        for (int it = 0; it < nsel; ++it) {
            float bmv = lm; int bi = li;
#pragma unroll
            for (int mask = 1; mask < 64; mask <<= 1) {
                const float ov = __shfl_xor(bmv, mask, 64);
                const int   oi = __shfl_xor(bi, mask, 64);
                if (ov > bmv || (ov == bmv && (unsigned)oi < (unsigned)bi)) {
                    bmv = ov; bi = oi;
                }
            }
            if (lane == (bi & 63)) {
                sc[wave][bi] = -INFINITY;
                lm = -INFINITY; li = -1;
                for (int j = lane; j < L; j += 64) {
                    const float s = sc[wave][j];
                    if (s > lm) { lm = s; li = j; }
                }
            }
            if (lane == 0) { selv[wave][it] = bmv; seli[wave][it] = bi; }
        }

        const float m = selv[wave][0];
        float e = 0.f;
        if (lane < nsel) e = expf(selv[wave][lane] - m);
        float Z = e;
#pragma unroll
        for (int mask = 1; mask < 32; mask <<= 1) Z += __shfl_xor(Z, mask, 64);
        if (lane < nsel) {
            const float w = e / Z;
            selw[wave][lane] = w;
            atomicAdd(&am[seli[wave][lane]], w);
        }

        float acc = 0.f;
        for (int i = 0; i < nsel; ++i) {
            const int idx = seli[wave][i];
            const float w = selw[wave][i];
            acc += w * Vb[(size_t)idx * DHEAD + lane];
        }
        ctx[(((size_t)(b * NTOK + q)) * HEADS + h) * DHEAD + lane] = acc;
    }

    __syncthreads();
    const float invH = 1.0f / (float)HEADS;
    float* arow = attn_out + ((size_t)(b * NTOK + q)) * NTOK;
    for (int j = tid; j < NTOK; j += 256) arow[j] = am[j] * invH;
}

// ---------------------------------------------------------------------------
extern "C" void kernel_launch(void* const* d_in, const int* in_sizes, int n_in,
                              void* d_out, int out_size, void* d_ws, size_t ws_size,
                              hipStream_t stream) {
    const float* x  = (const float*)d_in[0];
    const float* Wq = (const float*)d_in[1];
    const float* bq = (const float*)d_in[2];
    const float* Wk = (const float*)d_in[3];
    const float* bk = (const float*)d_in[4];
    const float* Wv = (const float*)d_in[5];
    const float* bv = (const float*)d_in[6];
    const float* Wo = (const float*)d_in[7];
    const float* bo = (const float*)d_in[8];

    const size_t MB = 1ull << 20;
    char* wsb = (char*)d_ws;
    float* Qws = (float*)(wsb + 0 * MB);
    float* Kws = (float*)(wsb + 16 * MB);
    float* Vws = (float*)(wsb + 32 * MB);
    float* ctx = (float*)(wsb + 48 * MB);
    ushort_t* xhi = (ushort_t*)(wsb + 64 * MB);
    ushort_t* xlo = (ushort_t*)(wsb + 72 * MB);
    ushort_t* wqh = (ushort_t*)(wsb + 80 * MB);
    ushort_t* wql = (ushort_t*)(wsb + 82 * MB);
    ushort_t* wkh = (ushort_t*)(wsb + 84 * MB);
    ushort_t* wkl = (ushort_t*)(wsb + 86 * MB);
    ushort_t* wvh = (ushort_t*)(wsb + 88 * MB);
    ushort_t* wvl = (ushort_t*)(wsb + 90 * MB);
    ushort_t* woh = (ushort_t*)(wsb + 92 * MB);
    ushort_t* wol = (ushort_t*)(wsb + 94 * MB);
    ushort_t* cxh = xhi;   // reuse (x dead after QKV)
    ushort_t* cxl = xlo;
    unsigned* Sws = (unsigned*)(wsb + 96 * MB);  // mono-key score chunk

    float* y    = (float*)d_out;
    float* attn = y + (size_t)BATCH * NTOK * DMODEL;

    const int NX = MROWS * DMODEL;
    const int NW = DMODEL * DMODEL;

    // ---- bf16 split conversions
    conv_split<<<NX / (256 * 4), 256, 0, stream>>>(x, xhi, xlo, NX);
    conv_split<<<NW / (256 * 4), 256, 0, stream>>>(Wq, wqh, wql, NW);
    conv_split<<<NW / (256 * 4), 256, 0, stream>>>(Wk, wkh, wkl, NW);
    conv_split<<<NW / (256 * 4), 256, 0, stream>>>(Wv, wvh, wvl, NW);
    conv_split<<<NW / (256 * 4), 256, 0, stream>>>(Wo, woh, wol, NW);

    // ---- Q/K/V projections (split-bf16 MFMA)
    dim3 ggrid(MROWS / 128, DMODEL / 64);
    gemm_split_mfma<<<ggrid, 256, 0, stream>>>(xhi, xlo, wqh, wql, bq, Qws, 1);
    gemm_split_mfma<<<ggrid, 256, 0, stream>>>(xhi, xlo, wkh, wkl, bk, Kws, 1);
    gemm_split_mfma<<<ggrid, 256, 0, stream>>>(xhi, xlo, wvh, wvl, bv, Vws, 1);

    // ---- attention
    const size_t base_bytes = 96 * MB;
    const size_t avail = (ws_size > base_bytes) ? ws_size - base_bytes : 0;
    int QC = 0;
    for (int cand = NTOK; cand >= 64; cand >>= 1) {
        const size_t need = (size_t)BATCH * HEADS * cand * NTOK * sizeof(float);
        if (need <= avail) { QC = cand; break; }
    }

    if (QC > 0) {
        const int nattn4 = BATCH * NTOK * NTOK / 4;
        zero_fill<<<(nattn4 + 255) / 256, 256, 0, stream>>>(attn, nattn4);
        for (int q0 = 0; q0 < NTOK; q0 += QC) {
            dim3 sgrid((q0 + QC) / 64, QC / 64, BATCH * HEADS);
            score_chunk<<<sgrid, 256, 0, stream>>>(Qws, Kws, Sws, q0, QC);
            dim3 selgrid(QC, BATCH * 4);
            select_v5<<<selgrid, 256, 0, stream>>>(Sws, Vws, ctx, attn, q0, QC);
        }
    } else {
        attn_kernel<<<BATCH * NTOK, 256, 0, stream>>>(Qws, Kws, Vws, ctx, attn);
    }

    // ---- output projection (split-bf16 MFMA)
    conv_split<<<NX / (256 * 4), 256, 0, stream>>>(ctx, cxh, cxl, NX);
    gemm_split_mfma<<<ggrid, 256, 0, stream>>>(cxh, cxl, woh, wol, bo, y, 0);
}

// Round 10
// 555.322 us; speedup vs baseline: 5.9215x; 1.1621x over previous
//
#include <hip/hip_runtime.h>
#include <hip/hip_bf16.h>
#include <math.h>

// Problem constants
#define BATCH   2
#define NTOK    2048
#define DMODEL  1024
#define HEADS   16
#define DHEAD   64
#define KSEL    32
#define MROWS   (BATCH * NTOK)   // 4096

typedef short     bf16x8 __attribute__((ext_vector_type(8)));
typedef float     f32x4  __attribute__((ext_vector_type(4)));
typedef unsigned short ushort_t;
typedef unsigned long long u64;

#define GLOAD_LDS16(g, l) \
    __builtin_amdgcn_global_load_lds((const __attribute__((address_space(1))) void*)(g), \
                                     (__attribute__((address_space(3))) void*)(l), 16, 0, 0)

// ---------------------------------------------------------------------------
// bf16 helpers
// ---------------------------------------------------------------------------
__device__ __forceinline__ ushort_t f2bf(float f) {
    unsigned u = __float_as_uint(f);
    unsigned r = (u + 0x7FFFu + ((u >> 16) & 1u)) >> 16;
    return (ushort_t)r;
}
__device__ __forceinline__ float bf2f(ushort_t h) {
    return __uint_as_float(((unsigned)h) << 16);
}

__global__ __launch_bounds__(256) void conv_split(const float* __restrict__ in,
                                                  ushort_t* __restrict__ hi,
                                                  ushort_t* __restrict__ lo, int n)
{
    const int i = (blockIdx.x * 256 + threadIdx.x) * 4;
    if (i + 3 < n) {
        const float4 v = *(const float4*)(in + i);
        ushort4 ph, pl;
        ph.x = f2bf(v.x); pl.x = f2bf(v.x - bf2f(ph.x));
        ph.y = f2bf(v.y); pl.y = f2bf(v.y - bf2f(ph.y));
        ph.z = f2bf(v.z); pl.z = f2bf(v.z - bf2f(ph.z));
        ph.w = f2bf(v.w); pl.w = f2bf(v.w - bf2f(ph.w));
        *(ushort4*)(hi + i) = ph;
        *(ushort4*)(lo + i) = pl;
    }
}

__global__ __launch_bounds__(256) void zero_fill(float* __restrict__ p, int n4)
{
    const int i = blockIdx.x * 256 + threadIdx.x;
    if (i < n4) ((float4*)p)[i] = (float4){0.f, 0.f, 0.f, 0.f};
}

// ---------------------------------------------------------------------------
// monotone key <-> float (bijective; order-preserving; 0 reserved for empty)
// ---------------------------------------------------------------------------
__device__ __forceinline__ unsigned mono_key(float f) {
    const unsigned u = __float_as_uint(f);
    return (u ^ (unsigned)(((int)u >> 31) | 0x80000000)) + 1u;
}
__device__ __forceinline__ float unmono(unsigned m) {
    const unsigned u = m - 1u;
    return __uint_as_float(u ^ (unsigned)(((int)(~u) >> 31) | 0x80000000));
}

// ---------------------------------------------------------------------------
// Split-bf16 MFMA GEMM: C = A*B^T + bias (fp32-class accuracy via 3 MFMAs)
//  mode 0: out fp32 [m][1024]
//  mode 1: out fp32 scatter [b,h,n,d]
//  mode 2: out 3-way bf16 split scatter [b,h,n,d] (oh/om/ol)
// ---------------------------------------------------------------------------
__global__ __launch_bounds__(256) void gemm_split_mfma(const ushort_t* __restrict__ Ahi,
                                                       const ushort_t* __restrict__ Alo,
                                                       const ushort_t* __restrict__ Bhi,
                                                       const ushort_t* __restrict__ Blo,
                                                       const float* __restrict__ bias,
                                                       float* __restrict__ out,
                                                       ushort_t* __restrict__ oh,
                                                       ushort_t* __restrict__ om,
                                                       ushort_t* __restrict__ ol,
                                                       int mode)
{
    __shared__ ushort_t AbufH[128 * 32];
    __shared__ ushort_t AbufL[128 * 32];
    __shared__ ushort_t BbufH[64 * 32];
    __shared__ ushort_t BbufL[64 * 32];

    const int tid  = threadIdx.x;
    const int wave = tid >> 6;
    const int lane = tid & 63;
    const int m0 = blockIdx.x * 128;
    const int n0 = blockIdx.y * 64;

    f32x4 acc[2][4];
#pragma unroll
    for (int i = 0; i < 2; ++i)
#pragma unroll
        for (int j = 0; j < 4; ++j) acc[i][j] = (f32x4){0.f, 0.f, 0.f, 0.f};

    const int ar0 = tid >> 2;
    const int ar1 = 64 + (tid >> 2);
    const int ak  = (tid & 3) << 3;
    const int br  = tid >> 2;

    const int fr = lane & 15;
    const int fk = (lane >> 4) << 3;

    for (int k0 = 0; k0 < DMODEL; k0 += 32) {
        __syncthreads();
        const size_t aoff0 = (size_t)(m0 + ar0) * DMODEL + k0 + ak;
        const size_t aoff1 = (size_t)(m0 + ar1) * DMODEL + k0 + ak;
        const size_t boff  = (size_t)(n0 + br) * DMODEL + k0 + ak;
        GLOAD_LDS16(Ahi + aoff0, AbufH + (size_t)tid * 8);
        GLOAD_LDS16(Ahi + aoff1, AbufH + (size_t)(256 + tid) * 8);
        GLOAD_LDS16(Alo + aoff0, AbufL + (size_t)tid * 8);
        GLOAD_LDS16(Alo + aoff1, AbufL + (size_t)(256 + tid) * 8);
        GLOAD_LDS16(Bhi + boff, BbufH + (size_t)tid * 8);
        GLOAD_LDS16(Blo + boff, BbufL + (size_t)tid * 8);
        __syncthreads();

        bf16x8 afh[2], afl[2], bfh[4], bfl[4];
#pragma unroll
        for (int mi = 0; mi < 2; ++mi) {
            const int ro = (wave * 32 + mi * 16 + fr) * 32 + fk;
            afh[mi] = *(const bf16x8*)(AbufH + ro);
            afl[mi] = *(const bf16x8*)(AbufL + ro);
        }
#pragma unroll
        for (int ni = 0; ni < 4; ++ni) {
            const int ro = (ni * 16 + fr) * 32 + fk;
            bfh[ni] = *(const bf16x8*)(BbufH + ro);
            bfl[ni] = *(const bf16x8*)(BbufL + ro);
        }

#pragma unroll
        for (int mi = 0; mi < 2; ++mi)
#pragma unroll
            for (int ni = 0; ni < 4; ++ni) {
                acc[mi][ni] = __builtin_amdgcn_mfma_f32_16x16x32_bf16(afh[mi], bfl[ni], acc[mi][ni], 0, 0, 0);
                acc[mi][ni] = __builtin_amdgcn_mfma_f32_16x16x32_bf16(afl[mi], bfh[ni], acc[mi][ni], 0, 0, 0);
                acc[mi][ni] = __builtin_amdgcn_mfma_f32_16x16x32_bf16(afh[mi], bfh[ni], acc[mi][ni], 0, 0, 0);
            }
    }

#pragma unroll
    for (int ni = 0; ni < 4; ++ni) {
        const int o = n0 + ni * 16 + (lane & 15);
        const float bv = bias[o];
#pragma unroll
        for (int mi = 0; mi < 2; ++mi) {
#pragma unroll
            for (int reg = 0; reg < 4; ++reg) {
                const int m = m0 + wave * 32 + mi * 16 + ((lane >> 4) << 2) + reg;
                const float v = acc[mi][ni][reg] + bv;
                if (mode == 0) {
                    out[(size_t)m * DMODEL + o] = v;
                } else {
                    const int bb = m >> 11;
                    const int n  = m & 2047;
                    const int hd = o >> 6;
                    const int d  = o & 63;
                    const size_t off = (((size_t)(bb * HEADS + hd)) * NTOK + n) * DHEAD + d;
                    if (mode == 1) {
                        out[off] = v;
                    } else {
                        const ushort_t h1 = f2bf(v);
                        const float r1 = v - bf2f(h1);
                        const ushort_t m1 = f2bf(r1);
                        const ushort_t l1 = f2bf(r1 - bf2f(m1));
                        oh[off] = h1; om[off] = m1; ol[off] = l1;
                    }
                }
            }
        }
    }
}

// ---------------------------------------------------------------------------
// score_mfma: S keys = mono(Q.K / 8) via 3-way-split bf16 MFMA (6 terms:
// hh, hm, mh, hl, lh, mm -> residual ~2^-25, fp32-class).
// Tile 128(q) x 64(k); K-depth staged 32/iter; 4 waves each own 32 q-rows.
// XOR swizzle pos=(c&3)^((row>>1)&3) keeps ds_read_b128 at 2-way (free).
// grid = ((q0+QC)>>6 kt, QC/128 qt, 32 bh)
// ---------------------------------------------------------------------------
__global__ __launch_bounds__(256) void score_mfma(const ushort_t* __restrict__ Qh,
                                                  const ushort_t* __restrict__ Qm,
                                                  const ushort_t* __restrict__ Ql,
                                                  const ushort_t* __restrict__ Kh,
                                                  const ushort_t* __restrict__ Km,
                                                  const ushort_t* __restrict__ Kl,
                                                  unsigned* __restrict__ S,
                                                  int q0, int QC)
{
    const int kt = blockIdx.x;
    const int qt = blockIdx.y;
    const int bh = blockIdx.z;
    const int qbase = q0 + qt * 128;
    if (kt * 64 > qbase + 127) return;   // fully non-causal tile

    __shared__ ushort_t QhB[128 * 32], QmB[128 * 32], QlB[128 * 32];  // 8 KB each
    __shared__ ushort_t KhB[64 * 32],  KmB[64 * 32],  KlB[64 * 32];   // 4 KB each

    const int tid  = threadIdx.x;
    const int wave = tid >> 6;
    const int lane = tid & 63;

    const size_t qgbase = ((size_t)bh * NTOK + qbase) * DHEAD;
    const size_t kgbase = ((size_t)bh * NTOK + kt * 64) * DHEAD;

    f32x4 acc[2][4];
#pragma unroll
    for (int i = 0; i < 2; ++i)
#pragma unroll
        for (int j = 0; j < 4; ++j) acc[i][j] = (f32x4){0.f, 0.f, 0.f, 0.f};

#pragma unroll
    for (int kit = 0; kit < 2; ++kit) {
        const int koff = kit * 32;
        __syncthreads();   // previous iteration's ds_reads complete
        // Q buffers: 512 chunks of 16B each (128 rows x 4 chunks)
#pragma unroll
        for (int i = 0; i < 2; ++i) {
            const int c = i * 256 + tid;
            const int row = c >> 2;
            const int pos = (c & 3) ^ ((row >> 1) & 3);
            const size_t g = qgbase + (size_t)row * DHEAD + koff + pos * 8;
            GLOAD_LDS16(Qh + g, QhB + (size_t)c * 8);
            GLOAD_LDS16(Qm + g, QmB + (size_t)c * 8);
            GLOAD_LDS16(Ql + g, QlB + (size_t)c * 8);
        }
        // K buffers: 256 chunks (64 rows x 4 chunks)
        {
            const int c = tid;
            const int row = c >> 2;
            const int pos = (c & 3) ^ ((row >> 1) & 3);
            const size_t g = kgbase + (size_t)row * DHEAD + koff + pos * 8;
            GLOAD_LDS16(Kh + g, KhB + (size_t)c * 8);
            GLOAD_LDS16(Km + g, KmB + (size_t)c * 8);
            GLOAD_LDS16(Kl + g, KlB + (size_t)c * 8);
        }
        __syncthreads();   // staging complete

        const int k8 = lane >> 4;   // 0..3 (8-elem chunk within the 32-deep buffer)

        bf16x8 qhf[2], qmf[2], qlf[2];
#pragma unroll
        for (int mi = 0; mi < 2; ++mi) {
            const int r = wave * 32 + mi * 16 + (lane & 15);
            const int ch = r * 4 + (k8 ^ ((r >> 1) & 3));
            qhf[mi] = *(const bf16x8*)(QhB + (size_t)ch * 8);
            qmf[mi] = *(const bf16x8*)(QmB + (size_t)ch * 8);
            qlf[mi] = *(const bf16x8*)(QlB + (size_t)ch * 8);
        }
        bf16x8 khf[4], kmf[4], klf[4];
#pragma unroll
        for (int ni = 0; ni < 4; ++ni) {
            const int r = ni * 16 + (lane & 15);
            const int ch = r * 4 + (k8 ^ ((r >> 1) & 3));
            khf[ni] = *(const bf16x8*)(KhB + (size_t)ch * 8);
            kmf[ni] = *(const bf16x8*)(KmB + (size_t)ch * 8);
            klf[ni] = *(const bf16x8*)(KlB + (size_t)ch * 8);
        }

#pragma unroll
        for (int mi = 0; mi < 2; ++mi)
#pragma unroll
            for (int ni = 0; ni < 4; ++ni) {
                acc[mi][ni] = __builtin_amdgcn_mfma_f32_16x16x32_bf16(qhf[mi], klf[ni], acc[mi][ni], 0, 0, 0);
                acc[mi][ni] = __builtin_amdgcn_mfma_f32_16x16x32_bf16(qlf[mi], khf[ni], acc[mi][ni], 0, 0, 0);
                acc[mi][ni] = __builtin_amdgcn_mfma_f32_16x16x32_bf16(qmf[mi], kmf[ni], acc[mi][ni], 0, 0, 0);
                acc[mi][ni] = __builtin_amdgcn_mfma_f32_16x16x32_bf16(qhf[mi], kmf[ni], acc[mi][ni], 0, 0, 0);
                acc[mi][ni] = __builtin_amdgcn_mfma_f32_16x16x32_bf16(qmf[mi], khf[ni], acc[mi][ni], 0, 0, 0);
                acc[mi][ni] = __builtin_amdgcn_mfma_f32_16x16x32_bf16(qhf[mi], khf[ni], acc[mi][ni], 0, 0, 0);
            }
    }

    // epilogue: C/D layout col=lane&15, row=(lane>>4)*4+reg
#pragma unroll
    for (int ni = 0; ni < 4; ++ni) {
        const int col = kt * 64 + ni * 16 + (lane & 15);
#pragma unroll
        for (int mi = 0; mi < 2; ++mi) {
#pragma unroll
            for (int reg = 0; reg < 4; ++reg) {
                const int mrow = wave * 32 + mi * 16 + ((lane >> 4) << 2) + reg;
                const int qlrow = qt * 128 + mrow;   // local q in chunk
                S[((size_t)bh * QC + qlrow) * NTOK + col] =
                    mono_key(acc[mi][ni][reg] * 0.125f);
            }
        }
    }
}

// ---------------------------------------------------------------------------
// select_v5: 16-bit-granular ballot threshold search on u32 mono keys.
// ---------------------------------------------------------------------------
template<int SLOTS>
__device__ __forceinline__ void select_task(const unsigned* __restrict__ Srow,
                                            const float* __restrict__ Vb,
                                            float* __restrict__ ctxRow,
                                            float* __restrict__ attnRow,
                                            int L, int nsel,
                                            int* __restrict__ sIdx,
                                            float* __restrict__ sE)
{
    const int lane = threadIdx.x & 63;

    unsigned km[SLOTS];
    unsigned lmax = 0u;
#pragma unroll
    for (int s = 0; s < SLOTS; ++s) {
        const int j = s * 64 + lane;
        unsigned m = 0u;
        if (j < L) m = Srow[j];
        km[s] = m;
        lmax = (m > lmax) ? m : lmax;
    }

    unsigned gmax = lmax, mmin = lmax;
#pragma unroll
    for (int d = 1; d < 64; d <<= 1) {
        const unsigned o1 = __shfl_xor(gmax, d, 64);
        const unsigned o2 = __shfl_xor(mmin, d, 64);
        gmax = (o1 > gmax) ? o1 : gmax;
        mmin = (o2 < mmin) ? o2 : mmin;
    }

    unsigned lo = (L >= 64) ? (mmin >> 16) : 1u;
    if (lo < 1u) lo = 1u;
    unsigned hi = gmax >> 16;
    while (lo < hi) {
        const unsigned mid = lo + ((hi - lo + 1u) >> 1);
        const unsigned midk = mid << 16;
        int cnt = 0;
#pragma unroll
        for (int s = 0; s < SLOTS; ++s)
            cnt += __popcll(__ballot(km[s] >= midk));
        if (cnt >= nsel) lo = mid; else hi = mid - 1u;
    }
    const unsigned Tk  = lo << 16;
    const unsigned Gk  = Tk | 0xFFFFu;

    int cnt_ge = 0, cnt_gt = 0;
#pragma unroll
    for (int s = 0; s < SLOTS; ++s) {
        cnt_ge += __popcll(__ballot(km[s] >= Tk));
        cnt_gt += __popcll(__ballot(km[s] > Gk));
    }

    unsigned selmask = 0u;
    if (cnt_ge == nsel) {
#pragma unroll
        for (int s = 0; s < SLOTS; ++s)
            selmask |= (km[s] >= Tk) ? (1u << s) : 0u;
    } else {
        unsigned bmask = 0u;
#pragma unroll
        for (int s = 0; s < SLOTS; ++s) {
            selmask |= (km[s] > Gk) ? (1u << s) : 0u;
            bmask   |= (km[s] >= Tk && km[s] <= Gk) ? (1u << s) : 0u;
        }
        int k_tie = nsel - cnt_gt;
        while (k_tie > 0) {
            u64 best = 0;
            unsigned bm = bmask;
            while (bm) {
                const int s = __builtin_ctz(bm);
                bm &= bm - 1u;
                const u64 k = ((u64)km[s] << 32) | (unsigned)~(s * 64 + lane);
                if (k > best) best = k;
            }
            u64 b = best;
#pragma unroll
            for (int d = 1; d < 64; d <<= 1) {
                const u64 o = __shfl_xor(b, d, 64);
                b = (o > b) ? o : b;
            }
            const unsigned gidx = ~(unsigned)b;
            if (lane == (int)(gidx & 63u)) {
                const unsigned bit = 1u << (gidx >> 6);
                selmask |= bit;
                bmask &= ~bit;
            }
            --k_tie;
        }
    }

    const int c = __popc(selmask);
    int pfx = c;
#pragma unroll
    for (int d = 1; d < 64; d <<= 1) {
        const int t = __shfl_up(pfx, d, 64);
        if (lane >= d) pfx += t;
    }
    pfx -= c;

    const float vmax = unmono(gmax);
    float esum = 0.f;
    unsigned msk = selmask;
    int pos = pfx;
    while (msk) {
        const int s = __builtin_ctz(msk);
        msk &= msk - 1u;
        const int j = s * 64 + lane;
        const float e = __expf(unmono(km[s]) - vmax);
        esum += e;
        sIdx[pos] = j;
        sE[pos] = e;
        ++pos;
    }

    float Z = esum;
#pragma unroll
    for (int d = 1; d < 64; d <<= 1) Z += __shfl_xor(Z, d, 64);
    const float rcpZ = 1.0f / Z;

    msk = selmask;
    pos = pfx;
    while (msk) {
        const int s = __builtin_ctz(msk);
        msk &= msk - 1u;
        const int j = s * 64 + lane;
        const float w = sE[pos] * rcpZ;
        ++pos;
        atomicAdd(&attnRow[j], w * (1.0f / (float)HEADS));
    }

    float acc = 0.f;
    for (int i = 0; i < nsel; ++i) {
        const int idx = sIdx[i];
        const float wi = sE[i] * rcpZ;
        acc += wi * Vb[(size_t)idx * DHEAD + lane];
    }
    ctxRow[lane] = acc;
}

__global__ __launch_bounds__(256) void select_v5(const unsigned* __restrict__ S,
                                                 const float* __restrict__ V,
                                                 float* __restrict__ ctx,
                                                 float* __restrict__ attn,
                                                 int q0, int QC)
{
    __shared__ int   sIdxAll[4][KSEL];
    __shared__ float sEAll[4][KSEL];

    const int wave = threadIdx.x >> 6;
    const int ql = blockIdx.x;
    const int b  = blockIdx.y >> 2;
    const int hg = blockIdx.y & 3;
    const int h  = hg * 4 + wave;
    const int q  = q0 + ql;
    const int L = q + 1;
    const int nsel = (L < KSEL) ? L : KSEL;

    const size_t bh = (size_t)(b * HEADS + h);
    const unsigned* Srow = S + (bh * QC + ql) * NTOK;
    const float* Vb   = V + bh * NTOK * DHEAD;
    float* ctxRow  = ctx + (((size_t)(b * NTOK + q)) * HEADS + h) * DHEAD;
    float* attnRow = attn + ((size_t)(b * NTOK + q)) * NTOK;

    if (q < 512)       select_task<8 >(Srow, Vb, ctxRow, attnRow, L, nsel, sIdxAll[wave], sEAll[wave]);
    else if (q < 1024) select_task<16>(Srow, Vb, ctxRow, attnRow, L, nsel, sIdxAll[wave], sEAll[wave]);
    else               select_task<32>(Srow, Vb, ctxRow, attnRow, L, nsel, sIdxAll[wave], sEAll[wave]);
}

// ---------------------------------------------------------------------------
extern "C" void kernel_launch(void* const* d_in, const int* in_sizes, int n_in,
                              void* d_out, int out_size, void* d_ws, size_t ws_size,
                              hipStream_t stream) {
    const float* x  = (const float*)d_in[0];
    const float* Wq = (const float*)d_in[1];
    const float* bq = (const float*)d_in[2];
    const float* Wk = (const float*)d_in[3];
    const float* bk = (const float*)d_in[4];
    const float* Wv = (const float*)d_in[5];
    const float* bv = (const float*)d_in[6];
    const float* Wo = (const float*)d_in[7];
    const float* bo = (const float*)d_in[8];

    const size_t MB = 1ull << 20;
    char* wsb = (char*)d_ws;
    float*    Vws = (float*)(wsb + 0 * MB);     // 16 MB fp32 [b,h,n,d]
    float*    ctx = (float*)(wsb + 16 * MB);    // 16 MB fp32
    ushort_t* xhi = (ushort_t*)(wsb + 32 * MB); // 8 MB
    ushort_t* xlo = (ushort_t*)(wsb + 40 * MB); // 8 MB
    ushort_t* wqh = (ushort_t*)(wsb + 48 * MB); // 2 MB each
    ushort_t* wql = (ushort_t*)(wsb + 50 * MB);
    ushort_t* wkh = (ushort_t*)(wsb + 52 * MB);
    ushort_t* wkl = (ushort_t*)(wsb + 54 * MB);
    ushort_t* wvh = (ushort_t*)(wsb + 56 * MB);
    ushort_t* wvl = (ushort_t*)(wsb + 58 * MB);
    ushort_t* woh = (ushort_t*)(wsb + 60 * MB);
    ushort_t* wol = (ushort_t*)(wsb + 62 * MB);
    ushort_t* Qh  = (ushort_t*)(wsb + 64 * MB); // 8 MB each, [b,h,n,d]
    ushort_t* Qm  = (ushort_t*)(wsb + 72 * MB);
    ushort_t* Ql  = (ushort_t*)(wsb + 80 * MB);
    ushort_t* Kh  = (ushort_t*)(wsb + 88 * MB);
    ushort_t* Km  = (ushort_t*)(wsb + 96 * MB);
    ushort_t* Kl  = (ushort_t*)(wsb + 104 * MB);
    unsigned* Sws = (unsigned*)(wsb + 112 * MB); // mono-key score chunk
    ushort_t* cxh = xhi;   // reuse (x splits dead after QKV projections)
    ushort_t* cxl = xlo;

    float* y    = (float*)d_out;
    float* attn = y + (size_t)BATCH * NTOK * DMODEL;

    const int NX = MROWS * DMODEL;
    const int NW = DMODEL * DMODEL;

    // ---- bf16 split conversions (gemm inputs)
    conv_split<<<NX / (256 * 4), 256, 0, stream>>>(x, xhi, xlo, NX);
    conv_split<<<NW / (256 * 4), 256, 0, stream>>>(Wq, wqh, wql, NW);
    conv_split<<<NW / (256 * 4), 256, 0, stream>>>(Wk, wkh, wkl, NW);
    conv_split<<<NW / (256 * 4), 256, 0, stream>>>(Wv, wvh, wvl, NW);
    conv_split<<<NW / (256 * 4), 256, 0, stream>>>(Wo, woh, wol, NW);

    // ---- projections: Q/K to 3-way split (mode 2), V to fp32 (mode 1)
    dim3 ggrid(MROWS / 128, DMODEL / 64);
    gemm_split_mfma<<<ggrid, 256, 0, stream>>>(xhi, xlo, wqh, wql, bq, nullptr, Qh, Qm, Ql, 2);
    gemm_split_mfma<<<ggrid, 256, 0, stream>>>(xhi, xlo, wkh, wkl, bk, nullptr, Kh, Km, Kl, 2);
    gemm_split_mfma<<<ggrid, 256, 0, stream>>>(xhi, xlo, wvh, wvl, bv, Vws, nullptr, nullptr, nullptr, 1);

    // ---- attention: largest power-of-two q-chunk (>=128) fitting after 112 MB
    const size_t base_bytes = 112 * MB;
    const size_t avail = (ws_size > base_bytes) ? ws_size - base_bytes : 0;
    int QC = 128;
    for (int cand = NTOK; cand >= 128; cand >>= 1) {
        const size_t need = (size_t)BATCH * HEADS * cand * NTOK * sizeof(unsigned);
        if (need <= avail) { QC = cand; break; }
    }

    const int nattn4 = BATCH * NTOK * NTOK / 4;
    zero_fill<<<(nattn4 + 255) / 256, 256, 0, stream>>>(attn, nattn4);
    for (int q0 = 0; q0 < NTOK; q0 += QC) {
        dim3 sgrid((q0 + QC) >> 6, QC / 128, BATCH * HEADS);
        score_mfma<<<sgrid, 256, 0, stream>>>(Qh, Qm, Ql, Kh, Km, Kl, Sws, q0, QC);
        dim3 selgrid(QC, BATCH * 4);
        select_v5<<<selgrid, 256, 0, stream>>>(Sws, Vws, ctx, attn, q0, QC);
    }

    // ---- output projection
    conv_split<<<NX / (256 * 4), 256, 0, stream>>>(ctx, cxh, cxl, NX);
    gemm_split_mfma<<<ggrid, 256, 0, stream>>>(cxh, cxl, woh, wol, bo, y, nullptr, nullptr, nullptr, 0);
}